// Round 1
// baseline (1321.215 us; speedup 1.0000x reference)
//
#include <hip/hip_runtime.h>
#include <math.h>

// ---------------------------------------------------------------------------
// Input_level_Adapeter: full pipeline on MI355X, fp32 correctness-first.
// d_out doubles as the I2 buffer (denoise writes it, final kernel reads the
// 3 channel values of its own pixel and overwrites them -> race-free).
// ---------------------------------------------------------------------------

#define BN_MUL 0.9999950000374997f   // 1/sqrt(1+1e-5)

static constexpr int BB   = 8;
static constexpr int HH   = 512;
static constexpr int WW   = 512;
static constexpr int HW   = HH * WW;
static constexpr int NTOK = 1024;    // (512/16)^2
static constexpr int DIMC = 64;

__device__ __forceinline__ float gelu_exact(float x) {
    return 0.5f * x * (1.0f + erff(x * 0.7071067811865476f));
}

// --- stride-2 3x3 conv + bias + BN (+ optional exact GELU), zero padding ---
__global__ void conv_s2_kernel(const float* __restrict__ in, const float* __restrict__ wt,
                               const float* __restrict__ bs, float* __restrict__ out,
                               int Cin, int Hin, int Win, int Cout, int doGelu, int total)
{
    int idx = blockIdx.x * blockDim.x + threadIdx.x;
    if (idx >= total) return;
    int Hout = Hin >> 1, Wout = Win >> 1;
    int ow = idx % Wout;
    int t  = idx / Wout;
    int oh = t % Hout; t /= Hout;
    int oc = t % Cout;
    int b  = t / Cout;

    const float* wrow = wt + oc * Cin * 9;
    float acc = bs[oc];
    int ih0 = oh * 2 - 1, iw0 = ow * 2 - 1;
    for (int ic = 0; ic < Cin; ++ic) {
        const float* ip = in + ((b * Cin + ic) * Hin) * Win;
        const float* wp = wrow + ic * 9;
        #pragma unroll
        for (int kh = 0; kh < 3; ++kh) {
            int ih = ih0 + kh;
            if (ih < 0 || ih >= Hin) continue;
            #pragma unroll
            for (int kw_ = 0; kw_ < 3; ++kw_) {
                int iw = iw0 + kw_;
                if (iw < 0 || iw >= Win) continue;
                acc += ip[ih * Win + iw] * wp[kh * 3 + kw_];
            }
        }
    }
    acc *= BN_MUL;
    if (doGelu) acc = gelu_exact(acc);
    out[idx] = acc;
}

// --- K = dx@kw^T + kb, V = dx@vw^T + vb; dx and K,V stored (B, C=64, N=1024) ---
__global__ void attn_kv_kernel(const float* __restrict__ dx,
                               const float* __restrict__ kw, const float* __restrict__ kb,
                               const float* __restrict__ vw, const float* __restrict__ vb,
                               float* __restrict__ kout, float* __restrict__ vout)
{
    int idx = blockIdx.x * blockDim.x + threadIdx.x;   // B*64*1024
    int n = idx & (NTOK - 1);
    int c = (idx >> 10) & 63;
    int b = idx >> 16;
    if (b >= BB) return;
    const float* dp  = dx + (b * DIMC) * NTOK + n;
    const float* kwr = kw + c * DIMC;
    const float* vwr = vw + c * DIMC;
    float ka = kb[c], va = vb[c];
    for (int cc = 0; cc < DIMC; ++cc) {
        float d = dp[cc * NTOK];
        ka += d * kwr[cc];
        va += d * vwr[cc];
    }
    kout[idx] = ka;
    vout[idx] = va;
}

// --- one block per (b,t): softmax(q K^T * scale) V -> proj -> scalar out ---
__global__ void attn_head_kernel(const float* __restrict__ kbuf, const float* __restrict__ vbuf,
                                 const float* __restrict__ q,
                                 const float* __restrict__ pw, const float* __restrict__ pb,
                                 const float* __restrict__ dw, const float* __restrict__ db,
                                 float* __restrict__ outv, int T)
{
    __shared__ float sc[NTOK];
    __shared__ float red[256];
    __shared__ float qsh[DIMC];
    __shared__ float osh[DIMC];
    __shared__ float psh[DIMC];
    int tid = threadIdx.x;
    int bt  = blockIdx.x;
    int b = bt / T, t = bt % T;

    if (tid < DIMC) qsh[tid] = q[t * DIMC + tid];
    __syncthreads();

    const float* kp = kbuf + (b * DIMC) * NTOK;
    const float* vp = vbuf + (b * DIMC) * NTOK;

    float lmax = -1e30f;
    #pragma unroll
    for (int r = 0; r < 4; ++r) {
        int n = tid + r * 256;
        float s = 0.f;
        for (int c = 0; c < DIMC; ++c) s += qsh[c] * kp[c * NTOK + n];
        s *= 0.125f;                      // 64^-0.5
        sc[n] = s;
        lmax = fmaxf(lmax, s);
    }
    red[tid] = lmax;
    __syncthreads();
    for (int off = 128; off > 0; off >>= 1) {
        if (tid < off) red[tid] = fmaxf(red[tid], red[tid + off]);
        __syncthreads();
    }
    float m = red[0];
    __syncthreads();

    float lsum = 0.f;
    #pragma unroll
    for (int r = 0; r < 4; ++r) {
        int n = tid + r * 256;
        float e = expf(sc[n] - m);
        sc[n] = e;
        lsum += e;
    }
    red[tid] = lsum;
    __syncthreads();
    for (int off = 128; off > 0; off >>= 1) {
        if (tid < off) red[tid] += red[tid + off];
        __syncthreads();
    }
    float Ssum = red[0];
    __syncthreads();

    // o[c] = sum_n a[n] * v[c,n]
    int c  = tid & 63, qq = tid >> 6;
    float part = 0.f;
    const float* vr = vp + c * NTOK + qq * 256;
    const float* sr = sc + qq * 256;
    for (int n = 0; n < 256; ++n) part += sr[n] * vr[n];
    red[tid] = part;
    __syncthreads();
    if (tid < DIMC)
        osh[tid] = (red[tid] + red[tid + 64] + red[tid + 128] + red[tid + 192]) / Ssum;
    __syncthreads();
    if (tid < DIMC) {
        float p = pb[tid];
        const float* pwr = pw + tid * DIMC;
        for (int cc = 0; cc < DIMC; ++cc) p += osh[cc] * pwr[cc];
        psh[tid] = p;
    }
    __syncthreads();
    if (tid == 0) {
        float r = db[0];
        for (int cc = 0; cc < DIMC; ++cc) r += psh[cc] * dw[cc];
        outv[bt] = r;
    }
}

// --- per-batch denoise params: gain, sigma, gaussian 1D kernels kx (r1), ky (r2) ---
__global__ void kp_param_kernel(const float* __restrict__ o, const float* __restrict__ gain_base,
                                float* __restrict__ par)
{
    int b = threadIdx.x;
    if (b >= BB) return;
    float o0 = o[b * 4 + 0], o1 = o[b * 4 + 1], o2 = o[b * 4 + 2], o3 = o[b * 4 + 3];
    float r1 = 0.1f * o0 + 3.0f;
    float r2 = 0.1f * o1 + 2.0f;
    float g  = o2 + gain_base[0];
    float sg = 1.0f / (1.0f + expf(-o3));
    float ex = expf(-0.5f / (r1 * r1));
    float nx = 1.0f / (2.0f * ex + 1.0f);
    float ey = expf(-0.5f / (r2 * r2));
    float ny = 1.0f / (2.0f * ey + 1.0f);
    float* p = par + b * 12;
    p[0] = g;  p[1] = sg;
    p[2] = ex * nx; p[3] = nx; p[4] = ex * nx;
    p[5] = ey * ny; p[6] = ny; p[7] = ey * ny;
}

// --- depthwise 3x3 gaussian blur (reflect pad) of gain*I1; unsharp; clip -> I2 ---
__global__ void denoise_kernel(const float* __restrict__ I1, const float* __restrict__ par,
                               float* __restrict__ I2, int total)
{
    int idx = blockIdx.x * blockDim.x + threadIdx.x;
    if (idx >= total) return;
    int w = idx & (WW - 1);
    int h = (idx >> 9) & (HH - 1);
    int t = idx >> 18;               // b*3 + c
    int b = t / 3;
    const float* p = par + b * 12;
    float g = p[0], sg = p[1];
    float kx0 = p[2], kx1 = p[3], kx2 = p[4];
    float ky0 = p[5], ky1 = p[6], ky2 = p[7];
    const float* ip = I1 + t * HW;
    float blur = 0.f;
    #pragma unroll
    for (int i = 0; i < 3; ++i) {
        int hh = h - 1 + i;
        hh = hh < 0 ? -hh : (hh >= HH ? 2 * HH - 2 - hh : hh);
        const float* row = ip + hh * WW;
        float ky = (i == 0) ? ky0 : (i == 1 ? ky1 : ky2);
        #pragma unroll
        for (int j = 0; j < 3; ++j) {
            int ww2 = w - 1 + j;
            ww2 = ww2 < 0 ? -ww2 : (ww2 >= WW ? 2 * WW - 2 - ww2 : ww2);
            float kx = (j == 0) ? kx0 : (j == 1 ? kx1 : kx2);
            blur += ky * kx * row[ww2];
        }
    }
    blur *= g;                                 // blur of gained image
    float v = blur + sg * (ip[h * WW + w] - blur);   // residual uses ORIGINAL img
    v = fminf(fmaxf(v, 1e-5f), 1.0f);
    I2[idx] = v;
}

// --- CCM (0.1*o + I) and dist (relu(o9)+1) per batch ---
__global__ void mp_param_kernel(const float* __restrict__ o, float* __restrict__ ccm,
                                float* __restrict__ dist)
{
    int b = threadIdx.x;
    if (b >= BB) return;
    for (int k = 0; k < 9; ++k)
        ccm[b * 9 + k] = 0.1f * o[b * 10 + k] + ((k % 4 == 0) ? 1.0f : 0.0f);
    float d = o[b * 10 + 9];
    dist[b] = (d > 0.f ? d : 0.f) + 1.0f;
}

// --- sum over pixels of I2^dist per (b, channel) ---
__global__ void wb_reduce_kernel(const float* __restrict__ I2, const float* __restrict__ dist,
                                 float* __restrict__ sums)
{
    __shared__ float red[256];
    int b = blockIdx.y;
    float d = dist[b];
    float l0 = 0.f, l1 = 0.f, l2 = 0.f;
    const float* base = I2 + b * 3 * HW;
    for (int pix = blockIdx.x * blockDim.x + threadIdx.x; pix < HW; pix += blockDim.x * gridDim.x) {
        l0 += powf(base[pix], d);
        l1 += powf(base[HW + pix], d);
        l2 += powf(base[2 * HW + pix], d);
    }
    float loc[3] = {l0, l1, l2};
    for (int c = 0; c < 3; ++c) {
        red[threadIdx.x] = loc[c];
        __syncthreads();
        for (int off = 128; off > 0; off >>= 1) {
            if (threadIdx.x < off) red[threadIdx.x] += red[threadIdx.x + off];
            __syncthreads();
        }
        if (threadIdx.x == 0) atomicAdd(&sums[b * 4 + c], red[0]);
        __syncthreads();
    }
}

// --- per-batch white-balance scale avg/ch ---
__global__ void wb_finalize_kernel(const float* __restrict__ sums, const float* __restrict__ dist,
                                   float* __restrict__ wbsc)
{
    int b = threadIdx.x;
    if (b >= BB) return;
    float d = dist[b], inv = 1.0f / d;
    float s0 = sums[b * 4 + 0], s1 = sums[b * 4 + 1], s2 = sums[b * 4 + 2];
    float ch0 = powf(s0 / (float)HW, inv);
    float ch1 = powf(s1 / (float)HW, inv);
    float ch2 = powf(s2 / (float)HW, inv);
    float avg = powf((s0 + s1 + s2) / (3.0f * (float)HW), inv);
    wbsc[b * 4 + 0] = avg / ch0;
    wbsc[b * 4 + 1] = avg / ch1;
    wbsc[b * 4 + 2] = avg / ch2;
}

// --- fused WB + CCM + NILUT residual MLP; reads/writes d_out in place ---
__global__ void __launch_bounds__(256) final_kernel(
    float* __restrict__ io,
    const float* __restrict__ wbsc, const float* __restrict__ ccm,
    const float* __restrict__ w0, const float* __restrict__ b0,
    const float* __restrict__ w1, const float* __restrict__ b1,
    const float* __restrict__ w2, const float* __restrict__ b2,
    const float* __restrict__ w3, const float* __restrict__ b3,
    const float* __restrict__ w4, const float* __restrict__ b4)
{
    // LDS weight cache: w0:0 b0:96 w1:128 b1:1152 w2:1184 b2:2208 w3:2240 b3:3264 w4:3296 b4:3392
    __shared__ __align__(16) float L[3408];
    int tid = threadIdx.x;
    for (int i = tid; i < 96;   i += 256) L[i]        = w0[i];
    for (int i = tid; i < 32;   i += 256) L[96 + i]   = b0[i];
    for (int i = tid; i < 1024; i += 256) L[128 + i]  = w1[i];
    for (int i = tid; i < 32;   i += 256) L[1152 + i] = b1[i];
    for (int i = tid; i < 1024; i += 256) L[1184 + i] = w2[i];
    for (int i = tid; i < 32;   i += 256) L[2208 + i] = b2[i];
    for (int i = tid; i < 1024; i += 256) L[2240 + i] = w3[i];
    for (int i = tid; i < 32;   i += 256) L[3264 + i] = b3[i];
    for (int i = tid; i < 96;   i += 256) L[3296 + i] = w4[i];
    for (int i = tid; i < 3;    i += 256) L[3392 + i] = b4[i];
    __syncthreads();

    int idx = blockIdx.x * 256 + tid;
    int b   = idx / HW;
    int pix = idx - b * HW;
    float* base = io + b * 3 * HW + pix;

    float i30 = base[0]        * wbsc[b * 4 + 0];
    float i31 = base[HW]       * wbsc[b * 4 + 1];
    float i32 = base[2 * HW]   * wbsc[b * 4 + 2];

    const float* cm = ccm + b * 9;
    float I4[3];
    I4[0] = fminf(fmaxf(cm[0] * i30 + cm[1] * i31 + cm[2] * i32, 1e-5f), 1.0f);
    I4[1] = fminf(fmaxf(cm[3] * i30 + cm[4] * i31 + cm[5] * i32, 1e-5f), 1.0f);
    I4[2] = fminf(fmaxf(cm[6] * i30 + cm[7] * i31 + cm[8] * i32, 1e-5f), 1.0f);

    float h[32], h2[32];
    #pragma unroll
    for (int j = 0; j < 32; ++j) {
        float a = L[96 + j] + L[j * 3] * I4[0] + L[j * 3 + 1] * I4[1] + L[j * 3 + 2] * I4[2];
        h[j] = a > 0.f ? a : 0.f;
    }
    #pragma unroll
    for (int j = 0; j < 32; ++j) {
        float a = L[1152 + j];
        const float4* wr = (const float4*)&L[128 + j * 32];
        #pragma unroll
        for (int k = 0; k < 8; ++k) {
            float4 wv = wr[k];
            a += wv.x * h[4 * k] + wv.y * h[4 * k + 1] + wv.z * h[4 * k + 2] + wv.w * h[4 * k + 3];
        }
        h2[j] = tanhf(a);
    }
    #pragma unroll
    for (int j = 0; j < 32; ++j) {
        float a = L[2208 + j];
        const float4* wr = (const float4*)&L[1184 + j * 32];
        #pragma unroll
        for (int k = 0; k < 8; ++k) {
            float4 wv = wr[k];
            a += wv.x * h2[4 * k] + wv.y * h2[4 * k + 1] + wv.z * h2[4 * k + 2] + wv.w * h2[4 * k + 3];
        }
        h[j] = tanhf(a);
    }
    #pragma unroll
    for (int j = 0; j < 32; ++j) {
        float a = L[3264 + j];
        const float4* wr = (const float4*)&L[2240 + j * 32];
        #pragma unroll
        for (int k = 0; k < 8; ++k) {
            float4 wv = wr[k];
            a += wv.x * h[4 * k] + wv.y * h[4 * k + 1] + wv.z * h[4 * k + 2] + wv.w * h[4 * k + 3];
        }
        h2[j] = tanhf(a);
    }
    #pragma unroll
    for (int d = 0; d < 3; ++d) {
        float a = L[3392 + d];
        const float4* wr = (const float4*)&L[3296 + d * 32];
        #pragma unroll
        for (int k = 0; k < 8; ++k) {
            float4 wv = wr[k];
            a += wv.x * h2[4 * k] + wv.y * h2[4 * k + 1] + wv.z * h2[4 * k + 2] + wv.w * h2[4 * k + 3];
        }
        a += I4[d];
        base[d * HW] = fminf(fmaxf(a, 0.f), 1.0f);
    }
}

extern "C" void kernel_launch(void* const* d_in, const int* in_sizes, int n_in,
                              void* d_out, int out_size, void* d_ws, size_t ws_size,
                              hipStream_t stream)
{
    // setup_inputs() dict order
    const float* I1      = (const float*)d_in[0];
    const float* kp_q    = (const float*)d_in[1];
    const float* kp_c1w  = (const float*)d_in[2];  const float* kp_c1b = (const float*)d_in[3];
    const float* kp_c2w  = (const float*)d_in[4];  const float* kp_c2b = (const float*)d_in[5];
    const float* kp_c3w  = (const float*)d_in[6];  const float* kp_c3b = (const float*)d_in[7];
    const float* kp_c4w  = (const float*)d_in[8];  const float* kp_c4b = (const float*)d_in[9];
    const float* kp_kw   = (const float*)d_in[10]; const float* kp_vw  = (const float*)d_in[11];
    const float* kp_pw   = (const float*)d_in[12]; const float* kp_dw  = (const float*)d_in[13];
    const float* kp_kb   = (const float*)d_in[14]; const float* kp_vb  = (const float*)d_in[15];
    const float* kp_pb   = (const float*)d_in[16]; const float* kp_db  = (const float*)d_in[17];
    const float* mp_q    = (const float*)d_in[18];
    const float* mp_c1w  = (const float*)d_in[19]; const float* mp_c1b = (const float*)d_in[20];
    const float* mp_c2w  = (const float*)d_in[21]; const float* mp_c2b = (const float*)d_in[22];
    const float* mp_c3w  = (const float*)d_in[23]; const float* mp_c3b = (const float*)d_in[24];
    const float* mp_c4w  = (const float*)d_in[25]; const float* mp_c4b = (const float*)d_in[26];
    const float* mp_kw   = (const float*)d_in[27]; const float* mp_vw  = (const float*)d_in[28];
    const float* mp_pw   = (const float*)d_in[29]; const float* mp_dw  = (const float*)d_in[30];
    const float* mp_kb   = (const float*)d_in[31]; const float* mp_vb  = (const float*)d_in[32];
    const float* mp_pb   = (const float*)d_in[33]; const float* mp_db  = (const float*)d_in[34];
    const float* gainb   = (const float*)d_in[35];
    const float* lw0 = (const float*)d_in[36]; const float* lb0 = (const float*)d_in[37];
    const float* lw1 = (const float*)d_in[38]; const float* lb1 = (const float*)d_in[39];
    const float* lw2 = (const float*)d_in[40]; const float* lb2 = (const float*)d_in[41];
    const float* lw3 = (const float*)d_in[42]; const float* lb3 = (const float*)d_in[43];
    const float* lw4 = (const float*)d_in[44]; const float* lb4 = (const float*)d_in[45];

    float* ws    = (float*)d_ws;
    float* ds1   = ws;                          // 8*8*256*256   = 4194304
    float* ds2   = ds1 + 8 * 8 * 256 * 256;     // 8*16*128*128  = 2097152
    float* ds3   = ds2 + 8 * 16 * 128 * 128;    // 8*32*64*64    = 1048576
    float* ds4   = ds3 + 8 * 32 * 64 * 64;      // 8*64*32*32    = 524288
    float* kbuf  = ds4 + 8 * 64 * 32 * 32;      // 524288
    float* vbuf  = kbuf + 8 * 64 * 1024;        // 524288
    float* attno = vbuf + 8 * 64 * 1024;        // 128
    float* par   = attno + 128;                 // 128
    float* ccm   = par + 128;                   // 128
    float* dist  = ccm + 128;                   // 32
    float* sums  = dist + 32;                   // 32
    float* wbsc  = sums + 32;                   // 32
    float* I2    = (float*)d_out;               // I2 lives in d_out

    const int n1 = 8 * 8 * 256 * 256, n2 = 8 * 16 * 128 * 128;
    const int n3 = 8 * 32 * 64 * 64,  n4 = 8 * 64 * 32 * 32;

    // --- Kernel_Predictor ---
    conv_s2_kernel<<<n1 / 256, 256, 0, stream>>>(I1,  kp_c1w, kp_c1b, ds1, 3,  512, 512, 8,  1, n1);
    conv_s2_kernel<<<n2 / 256, 256, 0, stream>>>(ds1, kp_c2w, kp_c2b, ds2, 8,  256, 256, 16, 1, n2);
    conv_s2_kernel<<<n3 / 256, 256, 0, stream>>>(ds2, kp_c3w, kp_c3b, ds3, 16, 128, 128, 32, 1, n3);
    conv_s2_kernel<<<n4 / 256, 256, 0, stream>>>(ds3, kp_c4w, kp_c4b, ds4, 32, 64,  64,  64, 0, n4);
    attn_kv_kernel<<<(BB * DIMC * NTOK) / 256, 256, 0, stream>>>(ds4, kp_kw, kp_kb, kp_vw, kp_vb, kbuf, vbuf);
    attn_head_kernel<<<BB * 4, 256, 0, stream>>>(kbuf, vbuf, kp_q, kp_pw, kp_pb, kp_dw, kp_db, attno, 4);
    kp_param_kernel<<<1, 64, 0, stream>>>(attno, gainb, par);

    // --- gain + gaussian unsharp denoise -> I2 (in d_out) ---
    denoise_kernel<<<(BB * 3 * HW) / 256, 256, 0, stream>>>(I1, par, I2, BB * 3 * HW);

    // --- Matrix_Predictor on I2 ---
    conv_s2_kernel<<<n1 / 256, 256, 0, stream>>>(I2,  mp_c1w, mp_c1b, ds1, 3,  512, 512, 8,  1, n1);
    conv_s2_kernel<<<n2 / 256, 256, 0, stream>>>(ds1, mp_c2w, mp_c2b, ds2, 8,  256, 256, 16, 1, n2);
    conv_s2_kernel<<<n3 / 256, 256, 0, stream>>>(ds2, mp_c3w, mp_c3b, ds3, 16, 128, 128, 32, 1, n3);
    conv_s2_kernel<<<n4 / 256, 256, 0, stream>>>(ds3, mp_c4w, mp_c4b, ds4, 32, 64,  64,  64, 0, n4);
    attn_kv_kernel<<<(BB * DIMC * NTOK) / 256, 256, 0, stream>>>(ds4, mp_kw, mp_kb, mp_vw, mp_vb, kbuf, vbuf);
    attn_head_kernel<<<BB * 10, 256, 0, stream>>>(kbuf, vbuf, mp_q, mp_pw, mp_pb, mp_dw, mp_db, attno, 10);
    mp_param_kernel<<<1, 64, 0, stream>>>(attno, ccm, dist);

    // --- shades-of-gray reduction ---
    hipMemsetAsync(sums, 0, 32 * sizeof(float), stream);
    wb_reduce_kernel<<<dim3(64, BB), 256, 0, stream>>>(I2, dist, sums);
    wb_finalize_kernel<<<1, 64, 0, stream>>>(sums, dist, wbsc);

    // --- fused WB + CCM + NILUT (in-place on d_out) ---
    final_kernel<<<(BB * HW) / 256, 256, 0, stream>>>(I2, wbsc, ccm,
        lw0, lb0, lw1, lb1, lw2, lb2, lw3, lb3, lw4, lb4);
}

// Round 3
// 730.449 us; speedup vs baseline: 1.8088x; 1.8088x over previous
//
#include <hip/hip_runtime.h>
#include <math.h>

// ---------------------------------------------------------------------------
// Input_level_Adapeter pipeline, round 3 (round-2 fix: __exp2f/__log2f clash
// with glibc math.h -> use __expf/__logf):
//  - final_kernel: scalar (SGPR) weight path, 2 px/thread, fast tanh (no LDS)
//  - convs: templated/unrolled, oc=blockIdx.y (scalar weights), OCTILE=2
//  - attn_kv: c=blockIdx.y (scalar weights)
// d_out doubles as the I2 buffer (denoise writes it; final kernel reads its
// own 3 channel values then overwrites them -> race-free).
// ---------------------------------------------------------------------------

#define BN_MUL 0.9999950000374997f   // 1/sqrt(1+1e-5)

static constexpr int BB   = 8;
static constexpr int HH   = 512;
static constexpr int WW   = 512;
static constexpr int HW   = HH * WW;
static constexpr int NTOK = 1024;    // (512/16)^2
static constexpr int DIMC = 64;

__device__ __forceinline__ float gelu_exact(float x) {
    return 0.5f * x * (1.0f + erff(x * 0.7071067811865476f));
}

// branch-free fast tanh: 1 - 2/(e^{2x}+1); saturates correctly at +-inf
__device__ __forceinline__ float tanh_fast(float x) {
    float e = __expf(2.0f * x);
    return 1.0f - 2.0f * __builtin_amdgcn_rcpf(e + 1.0f);
}

// --- stride-2 3x3 conv + bias + BN (+ optional exact GELU), zero padding ---
// grid: (Hout*Wout/256, Cout/2, B). oc uniform per block -> scalar weights.
// With s=2,p=1,k=3 only the top row / left col can be out of bounds.
template<int Cin, int Hin, bool GELU>
__global__ __launch_bounds__(256) void conv_s2(const float* __restrict__ in,
                                               const float* __restrict__ wt,
                                               const float* __restrict__ bs,
                                               float* __restrict__ out)
{
    constexpr int Win  = Hin, Hout = Hin / 2, Wout = Hin / 2;
    constexpr int WSH  = (Wout == 256) ? 8 : (Wout == 128) ? 7 : (Wout == 64) ? 6 : 5;
    constexpr int PLANE = Hout * Wout;

    const int sp  = blockIdx.x * 256 + threadIdx.x;
    const int ow  = sp & (Wout - 1);
    const int oh  = sp >> WSH;
    const int oc0 = blockIdx.y * 2;
    const int b   = blockIdx.z;
    const int Cout = (int)gridDim.y * 2;

    const float* wp0 = wt + oc0 * Cin * 9;       // uniform -> s_load
    const float* wp1 = wp0 + Cin * 9;
    float acc0 = bs[oc0], acc1 = bs[oc0 + 1];

    const int ih0 = oh * 2 - 1, iw0 = ow * 2 - 1;
    const float fh0 = (ih0 >= 0) ? 1.f : 0.f;
    const float fw0 = (iw0 >= 0) ? 1.f : 0.f;
    const int r0 = (ih0 >= 0) ? ih0 : 0;
    const int cc0 = (iw0 >= 0) ? iw0 : 0;

    const float* ip = in + (size_t)(b * Cin) * Hin * Win;
    #pragma unroll
    for (int ic = 0; ic < Cin; ++ic) {
        const float* pl = ip + ic * Hin * Win;
        const float* p0 = pl + r0 * Win;
        const float* p1 = pl + (ih0 + 1) * Win;
        const float* p2 = pl + (ih0 + 2) * Win;
        float  v00 = p0[cc0] * (fh0 * fw0);
        float2 va  = *(const float2*)(p0 + iw0 + 1);   // iw0+1 = 2ow, even-aligned
        float  v01 = va.x * fh0, v02 = va.y * fh0;
        float  v10 = p1[cc0] * fw0;
        float2 vb  = *(const float2*)(p1 + iw0 + 1);
        float  v20 = p2[cc0] * fw0;
        float2 vc  = *(const float2*)(p2 + iw0 + 1);
        const float* w0r = wp0 + ic * 9;
        const float* w1r = wp1 + ic * 9;
        acc0 += v00 * w0r[0] + v01 * w0r[1] + v02 * w0r[2]
              + v10 * w0r[3] + vb.x * w0r[4] + vb.y * w0r[5]
              + v20 * w0r[6] + vc.x * w0r[7] + vc.y * w0r[8];
        acc1 += v00 * w1r[0] + v01 * w1r[1] + v02 * w1r[2]
              + v10 * w1r[3] + vb.x * w1r[4] + vb.y * w1r[5]
              + v20 * w1r[6] + vc.x * w1r[7] + vc.y * w1r[8];
    }
    acc0 *= BN_MUL; acc1 *= BN_MUL;
    if (GELU) { acc0 = gelu_exact(acc0); acc1 = gelu_exact(acc1); }
    out[(b * Cout + oc0) * PLANE + sp]       = acc0;
    out[(b * Cout + oc0 + 1) * PLANE + sp]   = acc1;
}

// --- K = dx@kw^T + kb, V = dx@vw^T + vb; stored (B, C=64, N=1024) ---
// grid: (NTOK/256, 64, B); c uniform per block -> scalar weights.
__global__ __launch_bounds__(256) void attn_kv_kernel(const float* __restrict__ dx,
                               const float* __restrict__ kw, const float* __restrict__ kb,
                               const float* __restrict__ vw, const float* __restrict__ vb,
                               float* __restrict__ kout, float* __restrict__ vout)
{
    const int n = blockIdx.x * 256 + threadIdx.x;
    const int c = blockIdx.y;
    const int b = blockIdx.z;
    const float* dp  = dx + (b * DIMC) * NTOK + n;
    const float* kwr = kw + c * DIMC;    // uniform -> s_load
    const float* vwr = vw + c * DIMC;
    float ka = kb[c], va = vb[c];
    #pragma unroll
    for (int cc = 0; cc < DIMC; ++cc) {
        float d = dp[cc * NTOK];
        ka += d * kwr[cc];
        va += d * vwr[cc];
    }
    const int o = (b * DIMC + c) * NTOK + n;
    kout[o] = ka;
    vout[o] = va;
}

// --- one block per (b,t): softmax(q K^T * scale) V -> proj -> scalar out ---
__global__ void attn_head_kernel(const float* __restrict__ kbuf, const float* __restrict__ vbuf,
                                 const float* __restrict__ q,
                                 const float* __restrict__ pw, const float* __restrict__ pb,
                                 const float* __restrict__ dw, const float* __restrict__ db,
                                 float* __restrict__ outv, int T)
{
    __shared__ float sc[NTOK];
    __shared__ float red[256];
    __shared__ float qsh[DIMC];
    __shared__ float osh[DIMC];
    __shared__ float psh[DIMC];
    int tid = threadIdx.x;
    int bt  = blockIdx.x;
    int b = bt / T, t = bt % T;

    if (tid < DIMC) qsh[tid] = q[t * DIMC + tid];
    __syncthreads();

    const float* kp = kbuf + (b * DIMC) * NTOK;
    const float* vp = vbuf + (b * DIMC) * NTOK;

    float lmax = -1e30f;
    #pragma unroll
    for (int r = 0; r < 4; ++r) {
        int n = tid + r * 256;
        float s = 0.f;
        for (int c = 0; c < DIMC; ++c) s += qsh[c] * kp[c * NTOK + n];
        s *= 0.125f;                      // 64^-0.5
        sc[n] = s;
        lmax = fmaxf(lmax, s);
    }
    red[tid] = lmax;
    __syncthreads();
    for (int off = 128; off > 0; off >>= 1) {
        if (tid < off) red[tid] = fmaxf(red[tid], red[tid + off]);
        __syncthreads();
    }
    float m = red[0];
    __syncthreads();

    float lsum = 0.f;
    #pragma unroll
    for (int r = 0; r < 4; ++r) {
        int n = tid + r * 256;
        float e = __expf(sc[n] - m);
        sc[n] = e;
        lsum += e;
    }
    red[tid] = lsum;
    __syncthreads();
    for (int off = 128; off > 0; off >>= 1) {
        if (tid < off) red[tid] += red[tid + off];
        __syncthreads();
    }
    float Ssum = red[0];
    __syncthreads();

    int c  = tid & 63, qq = tid >> 6;
    float part = 0.f;
    const float* vr = vp + c * NTOK + qq * 256;
    const float* sr = sc + qq * 256;
    for (int n = 0; n < 256; ++n) part += sr[n] * vr[n];
    red[tid] = part;
    __syncthreads();
    if (tid < DIMC)
        osh[tid] = (red[tid] + red[tid + 64] + red[tid + 128] + red[tid + 192]) / Ssum;
    __syncthreads();
    if (tid < DIMC) {
        float p = pb[tid];
        const float* pwr = pw + tid * DIMC;
        for (int cc = 0; cc < DIMC; ++cc) p += osh[cc] * pwr[cc];
        psh[tid] = p;
    }
    __syncthreads();
    if (tid == 0) {
        float r = db[0];
        for (int cc = 0; cc < DIMC; ++cc) r += psh[cc] * dw[cc];
        outv[bt] = r;
    }
}

// --- per-batch denoise params: gain, sigma, gaussian 1D kernels kx (r1), ky (r2) ---
__global__ void kp_param_kernel(const float* __restrict__ o, const float* __restrict__ gain_base,
                                float* __restrict__ par)
{
    int b = threadIdx.x;
    if (b >= BB) return;
    float o0 = o[b * 4 + 0], o1 = o[b * 4 + 1], o2 = o[b * 4 + 2], o3 = o[b * 4 + 3];
    float r1 = 0.1f * o0 + 3.0f;
    float r2 = 0.1f * o1 + 2.0f;
    float g  = o2 + gain_base[0];
    float sg = 1.0f / (1.0f + expf(-o3));
    float ex = expf(-0.5f / (r1 * r1));
    float nx = 1.0f / (2.0f * ex + 1.0f);
    float ey = expf(-0.5f / (r2 * r2));
    float ny = 1.0f / (2.0f * ey + 1.0f);
    float* p = par + b * 12;
    p[0] = g;  p[1] = sg;
    p[2] = ex * nx; p[3] = nx; p[4] = ex * nx;
    p[5] = ey * ny; p[6] = ny; p[7] = ey * ny;
}

// --- depthwise 3x3 gaussian blur (reflect pad) of gain*I1; unsharp; clip -> I2 ---
__global__ void denoise_kernel(const float* __restrict__ I1, const float* __restrict__ par,
                               float* __restrict__ I2, int total)
{
    int idx = blockIdx.x * blockDim.x + threadIdx.x;
    if (idx >= total) return;
    int w = idx & (WW - 1);
    int h = (idx >> 9) & (HH - 1);
    int t = idx >> 18;               // b*3 + c
    int b = t / 3;
    const float* p = par + b * 12;
    float g = p[0], sg = p[1];
    float kx0 = p[2], kx1 = p[3], kx2 = p[4];
    float ky0 = p[5], ky1 = p[6], ky2 = p[7];
    const float* ip = I1 + t * HW;
    float blur = 0.f;
    #pragma unroll
    for (int i = 0; i < 3; ++i) {
        int hh = h - 1 + i;
        hh = hh < 0 ? -hh : (hh >= HH ? 2 * HH - 2 - hh : hh);
        const float* row = ip + hh * WW;
        float ky = (i == 0) ? ky0 : (i == 1 ? ky1 : ky2);
        #pragma unroll
        for (int j = 0; j < 3; ++j) {
            int ww2 = w - 1 + j;
            ww2 = ww2 < 0 ? -ww2 : (ww2 >= WW ? 2 * WW - 2 - ww2 : ww2);
            float kx = (j == 0) ? kx0 : (j == 1 ? kx1 : kx2);
            blur += ky * kx * row[ww2];
        }
    }
    blur *= g;                                       // blur of gained image
    float v = blur + sg * (ip[h * WW + w] - blur);   // residual uses ORIGINAL img
    v = fminf(fmaxf(v, 1e-5f), 1.0f);
    I2[idx] = v;
}

// --- CCM (0.1*o + I) and dist (relu(o9)+1) per batch ---
__global__ void mp_param_kernel(const float* __restrict__ o, float* __restrict__ ccm,
                                float* __restrict__ dist)
{
    int b = threadIdx.x;
    if (b >= BB) return;
    for (int k = 0; k < 9; ++k)
        ccm[b * 9 + k] = 0.1f * o[b * 10 + k] + ((k % 4 == 0) ? 1.0f : 0.0f);
    float d = o[b * 10 + 9];
    dist[b] = (d > 0.f ? d : 0.f) + 1.0f;
}

// --- sum over pixels of I2^dist per (b, channel); fast pow (x >= 1e-5 > 0) ---
__global__ void wb_reduce_kernel(const float* __restrict__ I2, const float* __restrict__ dist,
                                 float* __restrict__ sums)
{
    __shared__ float red[256];
    int b = blockIdx.y;
    float d = dist[b];
    float l0 = 0.f, l1 = 0.f, l2 = 0.f;
    const float* base = I2 + b * 3 * HW;
    for (int pix = blockIdx.x * blockDim.x + threadIdx.x; pix < HW; pix += blockDim.x * gridDim.x) {
        l0 += __expf(d * __logf(base[pix]));
        l1 += __expf(d * __logf(base[HW + pix]));
        l2 += __expf(d * __logf(base[2 * HW + pix]));
    }
    float loc[3] = {l0, l1, l2};
    for (int c = 0; c < 3; ++c) {
        red[threadIdx.x] = loc[c];
        __syncthreads();
        for (int off = 128; off > 0; off >>= 1) {
            if (threadIdx.x < off) red[threadIdx.x] += red[threadIdx.x + off];
            __syncthreads();
        }
        if (threadIdx.x == 0) atomicAdd(&sums[b * 4 + c], red[0]);
        __syncthreads();
    }
}

// --- per-batch white-balance scale avg/ch ---
__global__ void wb_finalize_kernel(const float* __restrict__ sums, const float* __restrict__ dist,
                                   float* __restrict__ wbsc)
{
    int b = threadIdx.x;
    if (b >= BB) return;
    float d = dist[b], inv = 1.0f / d;
    float s0 = sums[b * 4 + 0], s1 = sums[b * 4 + 1], s2 = sums[b * 4 + 2];
    float ch0 = powf(s0 / (float)HW, inv);
    float ch1 = powf(s1 / (float)HW, inv);
    float ch2 = powf(s2 / (float)HW, inv);
    float avg = powf((s0 + s1 + s2) / (3.0f * (float)HW), inv);
    wbsc[b * 4 + 0] = avg / ch0;
    wbsc[b * 4 + 1] = avg / ch1;
    wbsc[b * 4 + 2] = avg / ch2;
}

// --- fused WB + CCM + NILUT residual MLP; 2 px/thread; weights via scalar loads ---
__global__ void __launch_bounds__(256) final_kernel(
    float* __restrict__ io,
    const float* __restrict__ wbsc, const float* __restrict__ ccm,
    const float* __restrict__ w0, const float* __restrict__ b0,
    const float* __restrict__ w1, const float* __restrict__ b1,
    const float* __restrict__ w2, const float* __restrict__ b2,
    const float* __restrict__ w3, const float* __restrict__ b3,
    const float* __restrict__ w4, const float* __restrict__ b4)
{
    const int idx = blockIdx.x * 256 + threadIdx.x;   // BB*HW/2 threads
    const int b   = idx >> 17;                        // HW/2 = 131072; b block-uniform
    const int pix = (idx & (HW / 2 - 1)) * 2;
    float* base = io + b * 3 * HW + pix;

    const float s0 = wbsc[b * 4 + 0], s1 = wbsc[b * 4 + 1], s2 = wbsc[b * 4 + 2];
    const float2 c0 = *(const float2*)(base);
    const float2 c1 = *(const float2*)(base + HW);
    const float2 c2 = *(const float2*)(base + 2 * HW);

    const float* cm = ccm + b * 9;                    // block-uniform -> scalar
    float I4a[3], I4b[3];
    {
        float x0 = c0.x * s0, y0 = c1.x * s1, z0 = c2.x * s2;
        float x1 = c0.y * s0, y1 = c1.y * s1, z1 = c2.y * s2;
        #pragma unroll
        for (int d = 0; d < 3; ++d) {
            float m0 = cm[d * 3], m1 = cm[d * 3 + 1], m2 = cm[d * 3 + 2];
            I4a[d] = fminf(fmaxf(m0 * x0 + m1 * y0 + m2 * z0, 1e-5f), 1.0f);
            I4b[d] = fminf(fmaxf(m0 * x1 + m1 * y1 + m2 * z1, 1e-5f), 1.0f);
        }
    }

    float A0[32], A1[32], B0[32], B1[32];
    // layer 1: 3 -> 32, relu
    #pragma unroll
    for (int j = 0; j < 32; ++j) {
        float wj0 = w0[j * 3], wj1 = w0[j * 3 + 1], wj2 = w0[j * 3 + 2], bj = b0[j];
        float a = bj + wj0 * I4a[0] + wj1 * I4a[1] + wj2 * I4a[2];
        float c = bj + wj0 * I4b[0] + wj1 * I4b[1] + wj2 * I4b[2];
        A0[j] = a > 0.f ? a : 0.f;
        A1[j] = c > 0.f ? c : 0.f;
    }
    // layers 2-4: 32 -> 32, tanh  (weights: uniform addresses -> s_load)
    #pragma unroll
    for (int j = 0; j < 32; ++j) {
        float a = b1[j], c = a;
        const float4* wr = (const float4*)(w1 + j * 32);
        #pragma unroll
        for (int k = 0; k < 8; ++k) {
            float4 wv = wr[k];
            a += wv.x * A0[4*k] + wv.y * A0[4*k+1] + wv.z * A0[4*k+2] + wv.w * A0[4*k+3];
            c += wv.x * A1[4*k] + wv.y * A1[4*k+1] + wv.z * A1[4*k+2] + wv.w * A1[4*k+3];
        }
        B0[j] = tanh_fast(a); B1[j] = tanh_fast(c);
    }
    #pragma unroll
    for (int j = 0; j < 32; ++j) {
        float a = b2[j], c = a;
        const float4* wr = (const float4*)(w2 + j * 32);
        #pragma unroll
        for (int k = 0; k < 8; ++k) {
            float4 wv = wr[k];
            a += wv.x * B0[4*k] + wv.y * B0[4*k+1] + wv.z * B0[4*k+2] + wv.w * B0[4*k+3];
            c += wv.x * B1[4*k] + wv.y * B1[4*k+1] + wv.z * B1[4*k+2] + wv.w * B1[4*k+3];
        }
        A0[j] = tanh_fast(a); A1[j] = tanh_fast(c);
    }
    #pragma unroll
    for (int j = 0; j < 32; ++j) {
        float a = b3[j], c = a;
        const float4* wr = (const float4*)(w3 + j * 32);
        #pragma unroll
        for (int k = 0; k < 8; ++k) {
            float4 wv = wr[k];
            a += wv.x * A0[4*k] + wv.y * A0[4*k+1] + wv.z * A0[4*k+2] + wv.w * A0[4*k+3];
            c += wv.x * A1[4*k] + wv.y * A1[4*k+1] + wv.z * A1[4*k+2] + wv.w * A1[4*k+3];
        }
        B0[j] = tanh_fast(a); B1[j] = tanh_fast(c);
    }
    // layer 5: 32 -> 3, residual + clip, write back in place
    #pragma unroll
    for (int d = 0; d < 3; ++d) {
        float a = b4[d], c = a;
        const float4* wr = (const float4*)(w4 + d * 32);
        #pragma unroll
        for (int k = 0; k < 8; ++k) {
            float4 wv = wr[k];
            a += wv.x * B0[4*k] + wv.y * B0[4*k+1] + wv.z * B0[4*k+2] + wv.w * B0[4*k+3];
            c += wv.x * B1[4*k] + wv.y * B1[4*k+1] + wv.z * B1[4*k+2] + wv.w * B1[4*k+3];
        }
        a += I4a[d]; c += I4b[d];
        float2 o;
        o.x = fminf(fmaxf(a, 0.f), 1.0f);
        o.y = fminf(fmaxf(c, 0.f), 1.0f);
        *(float2*)(base + d * HW) = o;
    }
}

extern "C" void kernel_launch(void* const* d_in, const int* in_sizes, int n_in,
                              void* d_out, int out_size, void* d_ws, size_t ws_size,
                              hipStream_t stream)
{
    const float* I1      = (const float*)d_in[0];
    const float* kp_q    = (const float*)d_in[1];
    const float* kp_c1w  = (const float*)d_in[2];  const float* kp_c1b = (const float*)d_in[3];
    const float* kp_c2w  = (const float*)d_in[4];  const float* kp_c2b = (const float*)d_in[5];
    const float* kp_c3w  = (const float*)d_in[6];  const float* kp_c3b = (const float*)d_in[7];
    const float* kp_c4w  = (const float*)d_in[8];  const float* kp_c4b = (const float*)d_in[9];
    const float* kp_kw   = (const float*)d_in[10]; const float* kp_vw  = (const float*)d_in[11];
    const float* kp_pw   = (const float*)d_in[12]; const float* kp_dw  = (const float*)d_in[13];
    const float* kp_kb   = (const float*)d_in[14]; const float* kp_vb  = (const float*)d_in[15];
    const float* kp_pb   = (const float*)d_in[16]; const float* kp_db  = (const float*)d_in[17];
    const float* mp_q    = (const float*)d_in[18];
    const float* mp_c1w  = (const float*)d_in[19]; const float* mp_c1b = (const float*)d_in[20];
    const float* mp_c2w  = (const float*)d_in[21]; const float* mp_c2b = (const float*)d_in[22];
    const float* mp_c3w  = (const float*)d_in[23]; const float* mp_c3b = (const float*)d_in[24];
    const float* mp_c4w  = (const float*)d_in[25]; const float* mp_c4b = (const float*)d_in[26];
    const float* mp_kw   = (const float*)d_in[27]; const float* mp_vw  = (const float*)d_in[28];
    const float* mp_pw   = (const float*)d_in[29]; const float* mp_dw  = (const float*)d_in[30];
    const float* mp_kb   = (const float*)d_in[31]; const float* mp_vb  = (const float*)d_in[32];
    const float* mp_pb   = (const float*)d_in[33]; const float* mp_db  = (const float*)d_in[34];
    const float* gainb   = (const float*)d_in[35];
    const float* lw0 = (const float*)d_in[36]; const float* lb0 = (const float*)d_in[37];
    const float* lw1 = (const float*)d_in[38]; const float* lb1 = (const float*)d_in[39];
    const float* lw2 = (const float*)d_in[40]; const float* lb2 = (const float*)d_in[41];
    const float* lw3 = (const float*)d_in[42]; const float* lb3 = (const float*)d_in[43];
    const float* lw4 = (const float*)d_in[44]; const float* lb4 = (const float*)d_in[45];

    float* ws    = (float*)d_ws;
    float* ds1   = ws;                          // 8*8*256*256   = 4194304
    float* ds2   = ds1 + 8 * 8 * 256 * 256;     // 8*16*128*128  = 2097152
    float* ds3   = ds2 + 8 * 16 * 128 * 128;    // 8*32*64*64    = 1048576
    float* ds4   = ds3 + 8 * 32 * 64 * 64;      // 8*64*32*32    = 524288
    float* kbuf  = ds4 + 8 * 64 * 32 * 32;      // 524288
    float* vbuf  = kbuf + 8 * 64 * 1024;        // 524288
    float* attno = vbuf + 8 * 64 * 1024;        // 128
    float* par   = attno + 128;                 // 128
    float* ccm   = par + 128;                   // 128
    float* dist  = ccm + 128;                   // 32
    float* sums  = dist + 32;                   // 32
    float* wbsc  = sums + 32;                   // 32
    float* I2    = (float*)d_out;               // I2 lives in d_out

    // --- Kernel_Predictor ---
    conv_s2<3, 512, true ><<<dim3(256, 4,  BB), 256, 0, stream>>>(I1,  kp_c1w, kp_c1b, ds1);
    conv_s2<8, 256, true ><<<dim3(64,  8,  BB), 256, 0, stream>>>(ds1, kp_c2w, kp_c2b, ds2);
    conv_s2<16, 128, true><<<dim3(16,  16, BB), 256, 0, stream>>>(ds2, kp_c3w, kp_c3b, ds3);
    conv_s2<32, 64, false><<<dim3(4,   32, BB), 256, 0, stream>>>(ds3, kp_c4w, kp_c4b, ds4);
    attn_kv_kernel<<<dim3(NTOK / 256, DIMC, BB), 256, 0, stream>>>(ds4, kp_kw, kp_kb, kp_vw, kp_vb, kbuf, vbuf);
    attn_head_kernel<<<BB * 4, 256, 0, stream>>>(kbuf, vbuf, kp_q, kp_pw, kp_pb, kp_dw, kp_db, attno, 4);
    kp_param_kernel<<<1, 64, 0, stream>>>(attno, gainb, par);

    // --- gain + gaussian unsharp denoise -> I2 (in d_out) ---
    denoise_kernel<<<(BB * 3 * HW) / 256, 256, 0, stream>>>(I1, par, I2, BB * 3 * HW);

    // --- Matrix_Predictor on I2 ---
    conv_s2<3, 512, true ><<<dim3(256, 4,  BB), 256, 0, stream>>>(I2,  mp_c1w, mp_c1b, ds1);
    conv_s2<8, 256, true ><<<dim3(64,  8,  BB), 256, 0, stream>>>(ds1, mp_c2w, mp_c2b, ds2);
    conv_s2<16, 128, true><<<dim3(16,  16, BB), 256, 0, stream>>>(ds2, mp_c3w, mp_c3b, ds3);
    conv_s2<32, 64, false><<<dim3(4,   32, BB), 256, 0, stream>>>(ds3, mp_c4w, mp_c4b, ds4);
    attn_kv_kernel<<<dim3(NTOK / 256, DIMC, BB), 256, 0, stream>>>(ds4, mp_kw, mp_kb, mp_vw, mp_vb, kbuf, vbuf);
    attn_head_kernel<<<BB * 10, 256, 0, stream>>>(kbuf, vbuf, mp_q, mp_pw, mp_pb, mp_dw, mp_db, attno, 10);
    mp_param_kernel<<<1, 64, 0, stream>>>(attno, ccm, dist);

    // --- shades-of-gray reduction ---
    (void)hipMemsetAsync(sums, 0, 32 * sizeof(float), stream);
    wb_reduce_kernel<<<dim3(64, BB), 256, 0, stream>>>(I2, dist, sums);
    wb_finalize_kernel<<<1, 64, 0, stream>>>(sums, dist, wbsc);

    // --- fused WB + CCM + NILUT (in-place on d_out) ---
    final_kernel<<<(BB * HW / 2) / 256, 256, 0, stream>>>(I2, wbsc, ccm,
        lw0, lb0, lw1, lb1, lw2, lb2, lw3, lb3, lw4, lb4);
}

// Round 4
// 549.107 us; speedup vs baseline: 2.4061x; 1.3302x over previous
//
#include <hip/hip_runtime.h>
#include <math.h>

// ---------------------------------------------------------------------------
// Input_level_Adapeter pipeline, round 4:
//  - final_kernel: layers 2-4 of the NILUT MLP on MFMA f16 (16x16x32),
//    per-wave private LDS region for the C-layout -> A-layout transform.
//    Layers 1/5 + WB + CCM stay per-lane VALU. fp32 accumulation throughout.
//  - everything else identical to round 3 (passed, absmax 3.9e-3).
// d_out doubles as the I2 buffer (denoise writes it; final kernel reads its
// own 3 channel values then overwrites them -> race-free).
// ---------------------------------------------------------------------------

#define BN_MUL 0.9999950000374997f   // 1/sqrt(1+1e-5)

static constexpr int BB   = 8;
static constexpr int HH   = 512;
static constexpr int WW   = 512;
static constexpr int HW   = HH * WW;
static constexpr int NTOK = 1024;    // (512/16)^2
static constexpr int DIMC = 64;

typedef _Float16 f16x8 __attribute__((ext_vector_type(8)));
typedef _Float16 f16x2 __attribute__((ext_vector_type(2)));
typedef float    f32x4 __attribute__((ext_vector_type(4)));

__device__ __forceinline__ float gelu_exact(float x) {
    return 0.5f * x * (1.0f + erff(x * 0.7071067811865476f));
}

// branch-free fast tanh: 1 - 2/(e^{2x}+1); saturates correctly at +-inf
__device__ __forceinline__ float tanh_fast(float x) {
    float e = __expf(2.0f * x);
    return 1.0f - 2.0f * __builtin_amdgcn_rcpf(e + 1.0f);
}

// --- stride-2 3x3 conv + bias + BN (+ optional exact GELU), zero padding ---
template<int Cin, int Hin, bool GELU>
__global__ __launch_bounds__(256) void conv_s2(const float* __restrict__ in,
                                               const float* __restrict__ wt,
                                               const float* __restrict__ bs,
                                               float* __restrict__ out)
{
    constexpr int Win  = Hin, Hout = Hin / 2, Wout = Hin / 2;
    constexpr int WSH  = (Wout == 256) ? 8 : (Wout == 128) ? 7 : (Wout == 64) ? 6 : 5;
    constexpr int PLANE = Hout * Wout;

    const int sp  = blockIdx.x * 256 + threadIdx.x;
    const int ow  = sp & (Wout - 1);
    const int oh  = sp >> WSH;
    const int oc0 = blockIdx.y * 2;
    const int b   = blockIdx.z;
    const int Cout = (int)gridDim.y * 2;

    const float* wp0 = wt + oc0 * Cin * 9;       // uniform -> s_load
    const float* wp1 = wp0 + Cin * 9;
    float acc0 = bs[oc0], acc1 = bs[oc0 + 1];

    const int ih0 = oh * 2 - 1, iw0 = ow * 2 - 1;
    const float fh0 = (ih0 >= 0) ? 1.f : 0.f;
    const float fw0 = (iw0 >= 0) ? 1.f : 0.f;
    const int r0 = (ih0 >= 0) ? ih0 : 0;
    const int cc0 = (iw0 >= 0) ? iw0 : 0;

    const float* ip = in + (size_t)(b * Cin) * Hin * Win;
    #pragma unroll
    for (int ic = 0; ic < Cin; ++ic) {
        const float* pl = ip + ic * Hin * Win;
        const float* p0 = pl + r0 * Win;
        const float* p1 = pl + (ih0 + 1) * Win;
        const float* p2 = pl + (ih0 + 2) * Win;
        float  v00 = p0[cc0] * (fh0 * fw0);
        float2 va  = *(const float2*)(p0 + iw0 + 1);   // iw0+1 = 2ow, even-aligned
        float  v01 = va.x * fh0, v02 = va.y * fh0;
        float  v10 = p1[cc0] * fw0;
        float2 vb  = *(const float2*)(p1 + iw0 + 1);
        float  v20 = p2[cc0] * fw0;
        float2 vc  = *(const float2*)(p2 + iw0 + 1);
        const float* w0r = wp0 + ic * 9;
        const float* w1r = wp1 + ic * 9;
        acc0 += v00 * w0r[0] + v01 * w0r[1] + v02 * w0r[2]
              + v10 * w0r[3] + vb.x * w0r[4] + vb.y * w0r[5]
              + v20 * w0r[6] + vc.x * w0r[7] + vc.y * w0r[8];
        acc1 += v00 * w1r[0] + v01 * w1r[1] + v02 * w1r[2]
              + v10 * w1r[3] + vb.x * w1r[4] + vb.y * w1r[5]
              + v20 * w1r[6] + vc.x * w1r[7] + vc.y * w1r[8];
    }
    acc0 *= BN_MUL; acc1 *= BN_MUL;
    if (GELU) { acc0 = gelu_exact(acc0); acc1 = gelu_exact(acc1); }
    out[(b * Cout + oc0) * PLANE + sp]       = acc0;
    out[(b * Cout + oc0 + 1) * PLANE + sp]   = acc1;
}

// --- K = dx@kw^T + kb, V = dx@vw^T + vb; stored (B, C=64, N=1024) ---
__global__ __launch_bounds__(256) void attn_kv_kernel(const float* __restrict__ dx,
                               const float* __restrict__ kw, const float* __restrict__ kb,
                               const float* __restrict__ vw, const float* __restrict__ vb,
                               float* __restrict__ kout, float* __restrict__ vout)
{
    const int n = blockIdx.x * 256 + threadIdx.x;
    const int c = blockIdx.y;
    const int b = blockIdx.z;
    const float* dp  = dx + (b * DIMC) * NTOK + n;
    const float* kwr = kw + c * DIMC;    // uniform -> s_load
    const float* vwr = vw + c * DIMC;
    float ka = kb[c], va = vb[c];
    #pragma unroll
    for (int cc = 0; cc < DIMC; ++cc) {
        float d = dp[cc * NTOK];
        ka += d * kwr[cc];
        va += d * vwr[cc];
    }
    const int o = (b * DIMC + c) * NTOK + n;
    kout[o] = ka;
    vout[o] = va;
}

// --- one block per (b,t): softmax(q K^T * scale) V -> proj -> scalar out ---
__global__ void attn_head_kernel(const float* __restrict__ kbuf, const float* __restrict__ vbuf,
                                 const float* __restrict__ q,
                                 const float* __restrict__ pw, const float* __restrict__ pb,
                                 const float* __restrict__ dw, const float* __restrict__ db,
                                 float* __restrict__ outv, int T)
{
    __shared__ float sc[NTOK];
    __shared__ float red[256];
    __shared__ float qsh[DIMC];
    __shared__ float osh[DIMC];
    __shared__ float psh[DIMC];
    int tid = threadIdx.x;
    int bt  = blockIdx.x;
    int b = bt / T, t = bt % T;

    if (tid < DIMC) qsh[tid] = q[t * DIMC + tid];
    __syncthreads();

    const float* kp = kbuf + (b * DIMC) * NTOK;
    const float* vp = vbuf + (b * DIMC) * NTOK;

    float lmax = -1e30f;
    #pragma unroll
    for (int r = 0; r < 4; ++r) {
        int n = tid + r * 256;
        float s = 0.f;
        for (int c = 0; c < DIMC; ++c) s += qsh[c] * kp[c * NTOK + n];
        s *= 0.125f;                      // 64^-0.5
        sc[n] = s;
        lmax = fmaxf(lmax, s);
    }
    red[tid] = lmax;
    __syncthreads();
    for (int off = 128; off > 0; off >>= 1) {
        if (tid < off) red[tid] = fmaxf(red[tid], red[tid + off]);
        __syncthreads();
    }
    float m = red[0];
    __syncthreads();

    float lsum = 0.f;
    #pragma unroll
    for (int r = 0; r < 4; ++r) {
        int n = tid + r * 256;
        float e = __expf(sc[n] - m);
        sc[n] = e;
        lsum += e;
    }
    red[tid] = lsum;
    __syncthreads();
    for (int off = 128; off > 0; off >>= 1) {
        if (tid < off) red[tid] += red[tid + off];
        __syncthreads();
    }
    float Ssum = red[0];
    __syncthreads();

    int c  = tid & 63, qq = tid >> 6;
    float part = 0.f;
    const float* vr = vp + c * NTOK + qq * 256;
    const float* sr = sc + qq * 256;
    for (int n = 0; n < 256; ++n) part += sr[n] * vr[n];
    red[tid] = part;
    __syncthreads();
    if (tid < DIMC)
        osh[tid] = (red[tid] + red[tid + 64] + red[tid + 128] + red[tid + 192]) / Ssum;
    __syncthreads();
    if (tid < DIMC) {
        float p = pb[tid];
        const float* pwr = pw + tid * DIMC;
        for (int cc = 0; cc < DIMC; ++cc) p += osh[cc] * pwr[cc];
        psh[tid] = p;
    }
    __syncthreads();
    if (tid == 0) {
        float r = db[0];
        for (int cc = 0; cc < DIMC; ++cc) r += psh[cc] * dw[cc];
        outv[bt] = r;
    }
}

// --- per-batch denoise params ---
__global__ void kp_param_kernel(const float* __restrict__ o, const float* __restrict__ gain_base,
                                float* __restrict__ par)
{
    int b = threadIdx.x;
    if (b >= BB) return;
    float o0 = o[b * 4 + 0], o1 = o[b * 4 + 1], o2 = o[b * 4 + 2], o3 = o[b * 4 + 3];
    float r1 = 0.1f * o0 + 3.0f;
    float r2 = 0.1f * o1 + 2.0f;
    float g  = o2 + gain_base[0];
    float sg = 1.0f / (1.0f + expf(-o3));
    float ex = expf(-0.5f / (r1 * r1));
    float nx = 1.0f / (2.0f * ex + 1.0f);
    float ey = expf(-0.5f / (r2 * r2));
    float ny = 1.0f / (2.0f * ey + 1.0f);
    float* p = par + b * 12;
    p[0] = g;  p[1] = sg;
    p[2] = ex * nx; p[3] = nx; p[4] = ex * nx;
    p[5] = ey * ny; p[6] = ny; p[7] = ey * ny;
}

// --- depthwise 3x3 gaussian blur (reflect pad) of gain*I1; unsharp; clip -> I2 ---
__global__ void denoise_kernel(const float* __restrict__ I1, const float* __restrict__ par,
                               float* __restrict__ I2, int total)
{
    int idx = blockIdx.x * blockDim.x + threadIdx.x;
    if (idx >= total) return;
    int w = idx & (WW - 1);
    int h = (idx >> 9) & (HH - 1);
    int t = idx >> 18;               // b*3 + c
    int b = t / 3;
    const float* p = par + b * 12;
    float g = p[0], sg = p[1];
    float kx0 = p[2], kx1 = p[3], kx2 = p[4];
    float ky0 = p[5], ky1 = p[6], ky2 = p[7];
    const float* ip = I1 + t * HW;
    float blur = 0.f;
    #pragma unroll
    for (int i = 0; i < 3; ++i) {
        int hh = h - 1 + i;
        hh = hh < 0 ? -hh : (hh >= HH ? 2 * HH - 2 - hh : hh);
        const float* row = ip + hh * WW;
        float ky = (i == 0) ? ky0 : (i == 1 ? ky1 : ky2);
        #pragma unroll
        for (int j = 0; j < 3; ++j) {
            int ww2 = w - 1 + j;
            ww2 = ww2 < 0 ? -ww2 : (ww2 >= WW ? 2 * WW - 2 - ww2 : ww2);
            float kx = (j == 0) ? kx0 : (j == 1 ? kx1 : kx2);
            blur += ky * kx * row[ww2];
        }
    }
    blur *= g;                                       // blur of gained image
    float v = blur + sg * (ip[h * WW + w] - blur);   // residual uses ORIGINAL img
    v = fminf(fmaxf(v, 1e-5f), 1.0f);
    I2[idx] = v;
}

// --- CCM (0.1*o + I) and dist (relu(o9)+1) per batch ---
__global__ void mp_param_kernel(const float* __restrict__ o, float* __restrict__ ccm,
                                float* __restrict__ dist)
{
    int b = threadIdx.x;
    if (b >= BB) return;
    for (int k = 0; k < 9; ++k)
        ccm[b * 9 + k] = 0.1f * o[b * 10 + k] + ((k % 4 == 0) ? 1.0f : 0.0f);
    float d = o[b * 10 + 9];
    dist[b] = (d > 0.f ? d : 0.f) + 1.0f;
}

// --- sum over pixels of I2^dist per (b, channel); fast pow (x >= 1e-5 > 0) ---
__global__ void wb_reduce_kernel(const float* __restrict__ I2, const float* __restrict__ dist,
                                 float* __restrict__ sums)
{
    __shared__ float red[256];
    int b = blockIdx.y;
    float d = dist[b];
    float l0 = 0.f, l1 = 0.f, l2 = 0.f;
    const float* base = I2 + b * 3 * HW;
    for (int pix = blockIdx.x * blockDim.x + threadIdx.x; pix < HW; pix += blockDim.x * gridDim.x) {
        l0 += __expf(d * __logf(base[pix]));
        l1 += __expf(d * __logf(base[HW + pix]));
        l2 += __expf(d * __logf(base[2 * HW + pix]));
    }
    float loc[3] = {l0, l1, l2};
    for (int c = 0; c < 3; ++c) {
        red[threadIdx.x] = loc[c];
        __syncthreads();
        for (int off = 128; off > 0; off >>= 1) {
            if (threadIdx.x < off) red[threadIdx.x] += red[threadIdx.x + off];
            __syncthreads();
        }
        if (threadIdx.x == 0) atomicAdd(&sums[b * 4 + c], red[0]);
        __syncthreads();
    }
}

// --- per-batch white-balance scale avg/ch ---
__global__ void wb_finalize_kernel(const float* __restrict__ sums, const float* __restrict__ dist,
                                   float* __restrict__ wbsc)
{
    int b = threadIdx.x;
    if (b >= BB) return;
    float d = dist[b], inv = 1.0f / d;
    float s0 = sums[b * 4 + 0], s1 = sums[b * 4 + 1], s2 = sums[b * 4 + 2];
    float ch0 = powf(s0 / (float)HW, inv);
    float ch1 = powf(s1 / (float)HW, inv);
    float ch2 = powf(s2 / (float)HW, inv);
    float avg = powf((s0 + s1 + s2) / (3.0f * (float)HW), inv);
    wbsc[b * 4 + 0] = avg / ch0;
    wbsc[b * 4 + 1] = avg / ch1;
    wbsc[b * 4 + 2] = avg / ch2;
}

// --- fused WB + CCM + NILUT: layers 2-4 on MFMA f16, in-place on d_out ---
// Block = 256 thr = 4 waves; each wave owns 64 px and a private LDS region
// (64 rows x 72 f16, row stride 144 B -> 16B-aligned ds_read_b128 A-frags).
// MFMA f32_16x16x32_f16: arg0 A[m=lane&15][k=quad*8+j]; arg1 rows = out-
// neurons (same frag pattern); D: col(lane&15)=n, row(quad*4+reg)=m.
__global__ void __launch_bounds__(256) final_kernel(
    float* __restrict__ io,
    const float* __restrict__ wbsc, const float* __restrict__ ccm,
    const float* __restrict__ w0, const float* __restrict__ b0,
    const float* __restrict__ w1, const float* __restrict__ b1,
    const float* __restrict__ w2, const float* __restrict__ b2,
    const float* __restrict__ w3, const float* __restrict__ b3,
    const float* __restrict__ w4, const float* __restrict__ b4)
{
    constexpr int ROW = 72;                       // f16 per px row (144 B)
    __shared__ __align__(16) _Float16 LDS[4][64 * ROW];   // 36864 B
    const int tid  = threadIdx.x;
    const int wv   = tid >> 6;
    const int lane = tid & 63;
    const int nn   = lane & 15;
    const int quad = lane >> 4;
    _Float16* Wl = LDS[wv];                       // this wave's private region

    const int b   = blockIdx.x >> 10;             // 1024 blocks per image
    const int pix = (blockIdx.x * 256 + tid) & (HW - 1);
    float* base = io + b * 3 * HW + pix;

    // --- stage 0: load px, WB, CCM ---
    const float s0 = wbsc[b * 4 + 0], s1 = wbsc[b * 4 + 1], s2 = wbsc[b * 4 + 2];
    float v0 = base[0] * s0;
    float v1 = base[HW] * s1;
    float v2 = base[2 * HW] * s2;
    const float* cm = ccm + b * 9;                // block-uniform -> scalar
    float I4[3];
    #pragma unroll
    for (int d = 0; d < 3; ++d)
        I4[d] = fminf(fmaxf(cm[d * 3] * v0 + cm[d * 3 + 1] * v1 + cm[d * 3 + 2] * v2, 1e-5f), 1.0f);

    // --- stage 1: layer1 3->32 relu (VALU), write f16 row [px][k] ---
    #pragma unroll
    for (int j = 0; j < 32; j += 2) {
        float a0 = b0[j]   + w0[j*3]     * I4[0] + w0[j*3+1]     * I4[1] + w0[j*3+2]     * I4[2];
        float a1 = b0[j+1] + w0[(j+1)*3] * I4[0] + w0[(j+1)*3+1] * I4[1] + w0[(j+1)*3+2] * I4[2];
        f16x2 p;
        p[0] = (_Float16)fmaxf(a0, 0.f);
        p[1] = (_Float16)fmaxf(a1, 0.f);
        *(f16x2*)&Wl[lane * ROW + j] = p;
    }

    // --- resident weight B-frags + bias for layers 2-4 ---
    f16x8 wf[3][2];
    float bv[3][2];
    const float* wls[3] = { w1, w2, w3 };
    const float* bls[3] = { b1, b2, b3 };
    #pragma unroll
    for (int L = 0; L < 3; ++L) {
        #pragma unroll
        for (int h = 0; h < 2; ++h) {
            const float* wr = wls[L] + (16 * h + nn) * 32 + quad * 8;
            #pragma unroll
            for (int i = 0; i < 8; ++i) wf[L][h][i] = (_Float16)wr[i];
            bv[L][h] = bls[L][16 * h + nn];
        }
    }
    __syncthreads();

    // --- layers 2-4: MFMA + tanh, LDS round-trip per layer ---
    #pragma unroll
    for (int L = 0; L < 3; ++L) {
        f16x8 af[4];
        #pragma unroll
        for (int t = 0; t < 4; ++t)
            af[t] = *(const f16x8*)&Wl[(16 * t + nn) * ROW + quad * 8];
        __syncthreads();
        #pragma unroll
        for (int t = 0; t < 4; ++t) {
            #pragma unroll
            for (int h = 0; h < 2; ++h) {
                f32x4 c;
                c[0] = c[1] = c[2] = c[3] = bv[L][h];
                f32x4 d = __builtin_amdgcn_mfma_f32_16x16x32_f16(af[t], wf[L][h], c, 0, 0, 0);
                #pragma unroll
                for (int r = 0; r < 4; ++r)
                    Wl[(16 * t + quad * 4 + r) * ROW + 16 * h + nn] = (_Float16)tanh_fast(d[r]);
            }
        }
        __syncthreads();
    }

    // --- stage 5: layer5 32->3 (VALU) + residual + clip, in-place store ---
    float h4[32];
    #pragma unroll
    for (int g = 0; g < 4; ++g) {
        f16x8 rv = *(const f16x8*)&Wl[lane * ROW + g * 8];
        #pragma unroll
        for (int i = 0; i < 8; ++i) h4[g * 8 + i] = (float)rv[i];
    }
    #pragma unroll
    for (int d = 0; d < 3; ++d) {
        float a = b4[d];
        const float* wr = w4 + d * 32;            // uniform -> s_load
        #pragma unroll
        for (int k = 0; k < 32; ++k) a += h4[k] * wr[k];
        a += I4[d];
        base[d * HW] = fminf(fmaxf(a, 0.f), 1.0f);
    }
}

extern "C" void kernel_launch(void* const* d_in, const int* in_sizes, int n_in,
                              void* d_out, int out_size, void* d_ws, size_t ws_size,
                              hipStream_t stream)
{
    const float* I1      = (const float*)d_in[0];
    const float* kp_q    = (const float*)d_in[1];
    const float* kp_c1w  = (const float*)d_in[2];  const float* kp_c1b = (const float*)d_in[3];
    const float* kp_c2w  = (const float*)d_in[4];  const float* kp_c2b = (const float*)d_in[5];
    const float* kp_c3w  = (const float*)d_in[6];  const float* kp_c3b = (const float*)d_in[7];
    const float* kp_c4w  = (const float*)d_in[8];  const float* kp_c4b = (const float*)d_in[9];
    const float* kp_kw   = (const float*)d_in[10]; const float* kp_vw  = (const float*)d_in[11];
    const float* kp_pw   = (const float*)d_in[12]; const float* kp_dw  = (const float*)d_in[13];
    const float* kp_kb   = (const float*)d_in[14]; const float* kp_vb  = (const float*)d_in[15];
    const float* kp_pb   = (const float*)d_in[16]; const float* kp_db  = (const float*)d_in[17];
    const float* mp_q    = (const float*)d_in[18];
    const float* mp_c1w  = (const float*)d_in[19]; const float* mp_c1b = (const float*)d_in[20];
    const float* mp_c2w  = (const float*)d_in[21]; const float* mp_c2b = (const float*)d_in[22];
    const float* mp_c3w  = (const float*)d_in[23]; const float* mp_c3b = (const float*)d_in[24];
    const float* mp_c4w  = (const float*)d_in[25]; const float* mp_c4b = (const float*)d_in[26];
    const float* mp_kw   = (const float*)d_in[27]; const float* mp_vw  = (const float*)d_in[28];
    const float* mp_pw   = (const float*)d_in[29]; const float* mp_dw  = (const float*)d_in[30];
    const float* mp_kb   = (const float*)d_in[31]; const float* mp_vb  = (const float*)d_in[32];
    const float* mp_pb   = (const float*)d_in[33]; const float* mp_db  = (const float*)d_in[34];
    const float* gainb   = (const float*)d_in[35];
    const float* lw0 = (const float*)d_in[36]; const float* lb0 = (const float*)d_in[37];
    const float* lw1 = (const float*)d_in[38]; const float* lb1 = (const float*)d_in[39];
    const float* lw2 = (const float*)d_in[40]; const float* lb2 = (const float*)d_in[41];
    const float* lw3 = (const float*)d_in[42]; const float* lb3 = (const float*)d_in[43];
    const float* lw4 = (const float*)d_in[44]; const float* lb4 = (const float*)d_in[45];

    float* ws    = (float*)d_ws;
    float* ds1   = ws;                          // 8*8*256*256   = 4194304
    float* ds2   = ds1 + 8 * 8 * 256 * 256;     // 8*16*128*128  = 2097152
    float* ds3   = ds2 + 8 * 16 * 128 * 128;    // 8*32*64*64    = 1048576
    float* ds4   = ds3 + 8 * 32 * 64 * 64;      // 8*64*32*32    = 524288
    float* kbuf  = ds4 + 8 * 64 * 32 * 32;      // 524288
    float* vbuf  = kbuf + 8 * 64 * 1024;        // 524288
    float* attno = vbuf + 8 * 64 * 1024;        // 128
    float* par   = attno + 128;                 // 128
    float* ccm   = par + 128;                   // 128
    float* dist  = ccm + 128;                   // 32
    float* sums  = dist + 32;                   // 32
    float* wbsc  = sums + 32;                   // 32
    float* I2    = (float*)d_out;               // I2 lives in d_out

    // --- Kernel_Predictor ---
    conv_s2<3, 512, true ><<<dim3(256, 4,  BB), 256, 0, stream>>>(I1,  kp_c1w, kp_c1b, ds1);
    conv_s2<8, 256, true ><<<dim3(64,  8,  BB), 256, 0, stream>>>(ds1, kp_c2w, kp_c2b, ds2);
    conv_s2<16, 128, true><<<dim3(16,  16, BB), 256, 0, stream>>>(ds2, kp_c3w, kp_c3b, ds3);
    conv_s2<32, 64, false><<<dim3(4,   32, BB), 256, 0, stream>>>(ds3, kp_c4w, kp_c4b, ds4);
    attn_kv_kernel<<<dim3(NTOK / 256, DIMC, BB), 256, 0, stream>>>(ds4, kp_kw, kp_kb, kp_vw, kp_vb, kbuf, vbuf);
    attn_head_kernel<<<BB * 4, 256, 0, stream>>>(kbuf, vbuf, kp_q, kp_pw, kp_pb, kp_dw, kp_db, attno, 4);
    kp_param_kernel<<<1, 64, 0, stream>>>(attno, gainb, par);

    // --- gain + gaussian unsharp denoise -> I2 (in d_out) ---
    denoise_kernel<<<(BB * 3 * HW) / 256, 256, 0, stream>>>(I1, par, I2, BB * 3 * HW);

    // --- Matrix_Predictor on I2 ---
    conv_s2<3, 512, true ><<<dim3(256, 4,  BB), 256, 0, stream>>>(I2,  mp_c1w, mp_c1b, ds1);
    conv_s2<8, 256, true ><<<dim3(64,  8,  BB), 256, 0, stream>>>(ds1, mp_c2w, mp_c2b, ds2);
    conv_s2<16, 128, true><<<dim3(16,  16, BB), 256, 0, stream>>>(ds2, mp_c3w, mp_c3b, ds3);
    conv_s2<32, 64, false><<<dim3(4,   32, BB), 256, 0, stream>>>(ds3, mp_c4w, mp_c4b, ds4);
    attn_kv_kernel<<<dim3(NTOK / 256, DIMC, BB), 256, 0, stream>>>(ds4, mp_kw, mp_kb, mp_vw, mp_vb, kbuf, vbuf);
    attn_head_kernel<<<BB * 10, 256, 0, stream>>>(kbuf, vbuf, mp_q, mp_pw, mp_pb, mp_dw, mp_db, attno, 10);
    mp_param_kernel<<<1, 64, 0, stream>>>(attno, ccm, dist);

    // --- shades-of-gray reduction ---
    (void)hipMemsetAsync(sums, 0, 32 * sizeof(float), stream);
    wb_reduce_kernel<<<dim3(64, BB), 256, 0, stream>>>(I2, dist, sums);
    wb_finalize_kernel<<<1, 64, 0, stream>>>(sums, dist, wbsc);

    // --- fused WB + CCM + NILUT (in-place on d_out) ---
    final_kernel<<<BB * HW / 256, 256, 0, stream>>>(I2, wbsc, ccm,
        lw0, lb0, lw1, lb1, lw2, lb2, lw3, lb3, lw4, lb4);
}

// Round 5
// 458.958 us; speedup vs baseline: 2.8787x; 1.1964x over previous
//
#include <hip/hip_runtime.h>
#include <math.h>

// ---------------------------------------------------------------------------
// Input_level_Adapeter pipeline, round 5:
//  - conv_s2: OCTILE=4 (half the threads/loads/addressing of round 4)
//  - attn_head: 1024 threads (4x less serial work per thread)
//  - denoise: 2 px/thread (vertical), kp_param folded inline
//  - mp_param removed: dist inline in wb_reduce/wb_finalize, ccm inline in final
//  - final_kernel: unchanged MFMA f16 structure (94.8 us, near its tanh floor)
// d_out doubles as the I2 buffer (denoise writes it; final kernel reads its
// own 3 channel values then overwrites them -> race-free).
// ---------------------------------------------------------------------------

#define BN_MUL 0.9999950000374997f   // 1/sqrt(1+1e-5)

static constexpr int BB   = 8;
static constexpr int HH   = 512;
static constexpr int WW   = 512;
static constexpr int HW   = HH * WW;
static constexpr int NTOK = 1024;    // (512/16)^2
static constexpr int DIMC = 64;

typedef _Float16 f16x8 __attribute__((ext_vector_type(8)));
typedef _Float16 f16x2 __attribute__((ext_vector_type(2)));
typedef float    f32x4 __attribute__((ext_vector_type(4)));

__device__ __forceinline__ float gelu_exact(float x) {
    return 0.5f * x * (1.0f + erff(x * 0.7071067811865476f));
}

// branch-free fast tanh: 1 - 2/(e^{2x}+1); saturates correctly at +-inf
__device__ __forceinline__ float tanh_fast(float x) {
    float e = __expf(2.0f * x);
    return 1.0f - 2.0f * __builtin_amdgcn_rcpf(e + 1.0f);
}

// --- stride-2 3x3 conv + bias + BN (+ optional exact GELU), zero padding ---
// grid: (Hout*Wout/256, Cout/4, B). oc uniform per block -> scalar weights.
template<int Cin, int Hin, bool GELU>
__global__ __launch_bounds__(256) void conv_s2(const float* __restrict__ in,
                                               const float* __restrict__ wt,
                                               const float* __restrict__ bs,
                                               float* __restrict__ out)
{
    constexpr int Win  = Hin, Hout = Hin / 2, Wout = Hin / 2;
    constexpr int WSH  = (Wout == 256) ? 8 : (Wout == 128) ? 7 : (Wout == 64) ? 6 : 5;
    constexpr int PLANE = Hout * Wout;

    const int sp  = blockIdx.x * 256 + threadIdx.x;
    const int ow  = sp & (Wout - 1);
    const int oh  = sp >> WSH;
    const int oc0 = blockIdx.y * 4;
    const int b   = blockIdx.z;
    const int Cout = (int)gridDim.y * 4;

    float acc[4];
    #pragma unroll
    for (int o = 0; o < 4; ++o) acc[o] = bs[oc0 + o];

    const int ih0 = oh * 2 - 1, iw0 = ow * 2 - 1;
    const float fh0 = (ih0 >= 0) ? 1.f : 0.f;
    const float fw0 = (iw0 >= 0) ? 1.f : 0.f;
    const int r0 = (ih0 >= 0) ? ih0 : 0;
    const int cc0 = (iw0 >= 0) ? iw0 : 0;

    const float* ip = in + (size_t)(b * Cin) * Hin * Win;
    #pragma unroll
    for (int ic = 0; ic < Cin; ++ic) {
        const float* pl = ip + ic * Hin * Win;
        const float* p0 = pl + r0 * Win;
        const float* p1 = pl + (ih0 + 1) * Win;
        const float* p2 = pl + (ih0 + 2) * Win;
        float  v00 = p0[cc0] * (fh0 * fw0);
        float2 va  = *(const float2*)(p0 + iw0 + 1);   // iw0+1 = 2ow, even-aligned
        float  v01 = va.x * fh0, v02 = va.y * fh0;
        float  v10 = p1[cc0] * fw0;
        float2 vb  = *(const float2*)(p1 + iw0 + 1);
        float  v20 = p2[cc0] * fw0;
        float2 vc  = *(const float2*)(p2 + iw0 + 1);
        #pragma unroll
        for (int o = 0; o < 4; ++o) {
            const float* wr = wt + ((oc0 + o) * Cin + ic) * 9;   // uniform -> s_load
            acc[o] += v00 * wr[0] + v01 * wr[1] + v02 * wr[2]
                    + v10 * wr[3] + vb.x * wr[4] + vb.y * wr[5]
                    + v20 * wr[6] + vc.x * wr[7] + vc.y * wr[8];
        }
    }
    #pragma unroll
    for (int o = 0; o < 4; ++o) {
        float a = acc[o] * BN_MUL;
        if (GELU) a = gelu_exact(a);
        out[(b * Cout + oc0 + o) * PLANE + sp] = a;
    }
}

// --- K = dx@kw^T + kb, V = dx@vw^T + vb; stored (B, C=64, N=1024) ---
__global__ __launch_bounds__(256) void attn_kv_kernel(const float* __restrict__ dx,
                               const float* __restrict__ kw, const float* __restrict__ kb,
                               const float* __restrict__ vw, const float* __restrict__ vb,
                               float* __restrict__ kout, float* __restrict__ vout)
{
    const int n = blockIdx.x * 256 + threadIdx.x;
    const int c = blockIdx.y;
    const int b = blockIdx.z;
    const float* dp  = dx + (b * DIMC) * NTOK + n;
    const float* kwr = kw + c * DIMC;    // uniform -> s_load
    const float* vwr = vw + c * DIMC;
    float ka = kb[c], va = vb[c];
    #pragma unroll
    for (int cc = 0; cc < DIMC; ++cc) {
        float d = dp[cc * NTOK];
        ka += d * kwr[cc];
        va += d * vwr[cc];
    }
    const int o = (b * DIMC + c) * NTOK + n;
    kout[o] = ka;
    vout[o] = va;
}

// --- one block per (b,t), 1024 threads: softmax(q K^T) V -> proj -> scalar ---
__global__ __launch_bounds__(1024) void attn_head_kernel(
                                 const float* __restrict__ kbuf, const float* __restrict__ vbuf,
                                 const float* __restrict__ q,
                                 const float* __restrict__ pw, const float* __restrict__ pb,
                                 const float* __restrict__ dw, const float* __restrict__ db,
                                 float* __restrict__ outv, int T)
{
    __shared__ float sc[NTOK];
    __shared__ float red[1024];
    __shared__ float qsh[DIMC];
    __shared__ float osh[DIMC];
    __shared__ float psh[DIMC];
    const int tid = threadIdx.x;
    const int bt  = blockIdx.x;
    const int b = bt / T, t = bt - b * T;

    if (tid < DIMC) qsh[tid] = q[t * DIMC + tid];
    __syncthreads();

    const float* kp = kbuf + (b * DIMC) * NTOK;
    const float* vp = vbuf + (b * DIMC) * NTOK;

    // one token per thread
    float s = 0.f;
    #pragma unroll
    for (int c = 0; c < DIMC; ++c) s += qsh[c] * kp[c * NTOK + tid];
    s *= 0.125f;                      // 64^-0.5

    red[tid] = s;
    __syncthreads();
    for (int off = 512; off > 0; off >>= 1) {
        if (tid < off) red[tid] = fmaxf(red[tid], red[tid + off]);
        __syncthreads();
    }
    float m = red[0];
    __syncthreads();

    float e = __expf(s - m);
    sc[tid] = e;
    red[tid] = e;
    __syncthreads();
    for (int off = 512; off > 0; off >>= 1) {
        if (tid < off) red[tid] += red[tid + off];
        __syncthreads();
    }
    float Ssum = red[0];
    __syncthreads();

    // o[c] = sum_n a[n] * v[c,n]; 16-way split over n
    const int c  = tid & 63, qq = tid >> 6;
    float part = 0.f;
    const float* vr = vp + c * NTOK + qq * 64;
    const float* sr = sc + qq * 64;
    #pragma unroll
    for (int n = 0; n < 64; ++n) part += sr[n] * vr[n];
    red[tid] = part;
    __syncthreads();
    if (tid < DIMC) {
        float o = 0.f;
        #pragma unroll
        for (int k = 0; k < 16; ++k) o += red[tid + k * 64];
        osh[tid] = o / Ssum;
    }
    __syncthreads();
    if (tid < DIMC) {
        float p = pb[tid];
        const float* pwr = pw + tid * DIMC;
        #pragma unroll
        for (int cc = 0; cc < DIMC; ++cc) p += osh[cc] * pwr[cc];
        psh[tid] = p;
    }
    __syncthreads();
    if (tid == 0) {
        float r = db[0];
        #pragma unroll
        for (int cc = 0; cc < DIMC; ++cc) r += psh[cc] * dw[cc];
        outv[bt] = r;
    }
}

// --- gain + gaussian unsharp (reflect); 2 px/thread vertical; params inline ---
__global__ void denoise_kernel(const float* __restrict__ I1, const float* __restrict__ attno,
                               const float* __restrict__ gain_base, float* __restrict__ I2)
{
    const int idx = blockIdx.x * 256 + threadIdx.x;   // BB*3*HW/2 threads
    const int w  = idx & (WW - 1);
    const int h2 = (idx >> 9) & (HH / 2 - 1);
    const int t  = idx >> 17;               // b*3 + c
    const int b  = t / 3;

    // kp params (recomputed per thread; b block-uniform -> mostly scalar)
    const float o0 = attno[b * 4 + 0], o1 = attno[b * 4 + 1];
    const float o2 = attno[b * 4 + 2], o3 = attno[b * 4 + 3];
    const float r1 = 0.1f * o0 + 3.0f;
    const float r2 = 0.1f * o1 + 2.0f;
    const float g  = o2 + gain_base[0];
    const float sg = 1.0f / (1.0f + __expf(-o3));
    const float ex = __expf(-0.5f / (r1 * r1));
    const float nx = 1.0f / (2.0f * ex + 1.0f);
    const float ey = __expf(-0.5f / (r2 * r2));
    const float ny = 1.0f / (2.0f * ey + 1.0f);
    const float kx0 = ex * nx, kx1 = nx;   // kx2 == kx0 (symmetric)
    const float ky0 = ey * ny, ky1 = ny;

    const int h0 = h2 * 2;
    const float* ip = I1 + (size_t)t * HW;
    int ra = h0 - 1; ra = (ra < 0) ? 1 : ra;
    int rd = h0 + 2; rd = (rd >= HH) ? (2 * HH - 2 - rd) : rd;
    int c0 = w - 1;  c0 = (c0 < 0) ? 1 : c0;
    int c2 = w + 1;  c2 = (c2 >= WW) ? (WW - 2) : c2;
    const int rows[4] = { ra, h0, h0 + 1, rd };

    float rs[4], vm[4];
    #pragma unroll
    for (int i = 0; i < 4; ++i) {
        const float* rp = ip + rows[i] * WW;
        float a = rp[c0], mday = rp[w], z = rp[c2];
        vm[i] = mday;
        rs[i] = kx0 * (a + z) + kx1 * mday;
    }
    float blur0 = g * (ky0 * (rs[0] + rs[2]) + ky1 * rs[1]);
    float blur1 = g * (ky0 * (rs[1] + rs[3]) + ky1 * rs[2]);
    float out0 = blur0 + sg * (vm[1] - blur0);
    float out1 = blur1 + sg * (vm[2] - blur1);
    out0 = fminf(fmaxf(out0, 1e-5f), 1.0f);
    out1 = fminf(fmaxf(out1, 1e-5f), 1.0f);
    float* op = I2 + (size_t)t * HW + h0 * WW + w;
    op[0]  = out0;
    op[WW] = out1;
}

// --- sum over pixels of I2^dist per (b, channel); dist inline from attno ---
__global__ void wb_reduce_kernel(const float* __restrict__ I2, const float* __restrict__ attno,
                                 float* __restrict__ sums)
{
    __shared__ float red[256];
    int b = blockIdx.y;
    float d = attno[b * 10 + 9];
    d = (d > 0.f ? d : 0.f) + 1.0f;
    float l0 = 0.f, l1 = 0.f, l2 = 0.f;
    const float* base = I2 + b * 3 * HW;
    for (int pix = blockIdx.x * blockDim.x + threadIdx.x; pix < HW; pix += blockDim.x * gridDim.x) {
        l0 += __expf(d * __logf(base[pix]));
        l1 += __expf(d * __logf(base[HW + pix]));
        l2 += __expf(d * __logf(base[2 * HW + pix]));
    }
    float loc[3] = {l0, l1, l2};
    for (int c = 0; c < 3; ++c) {
        red[threadIdx.x] = loc[c];
        __syncthreads();
        for (int off = 128; off > 0; off >>= 1) {
            if (threadIdx.x < off) red[threadIdx.x] += red[threadIdx.x + off];
            __syncthreads();
        }
        if (threadIdx.x == 0) atomicAdd(&sums[b * 4 + c], red[0]);
        __syncthreads();
    }
}

// --- per-batch white-balance scale avg/ch; dist inline ---
__global__ void wb_finalize_kernel(const float* __restrict__ sums, const float* __restrict__ attno,
                                   float* __restrict__ wbsc)
{
    int b = threadIdx.x;
    if (b >= BB) return;
    float d = attno[b * 10 + 9];
    d = (d > 0.f ? d : 0.f) + 1.0f;
    float inv = 1.0f / d;
    float s0 = sums[b * 4 + 0], s1 = sums[b * 4 + 1], s2 = sums[b * 4 + 2];
    float ch0 = powf(s0 / (float)HW, inv);
    float ch1 = powf(s1 / (float)HW, inv);
    float ch2 = powf(s2 / (float)HW, inv);
    float avg = powf((s0 + s1 + s2) / (3.0f * (float)HW), inv);
    wbsc[b * 4 + 0] = avg / ch0;
    wbsc[b * 4 + 1] = avg / ch1;
    wbsc[b * 4 + 2] = avg / ch2;
}

// --- fused WB + CCM + NILUT: layers 2-4 on MFMA f16, in-place on d_out ---
// Block = 256 thr = 4 waves; each wave owns 64 px and a private LDS region
// (64 rows x 72 f16, row stride 144 B -> 16B-aligned ds_read_b128 A-frags).
__global__ void __launch_bounds__(256) final_kernel(
    float* __restrict__ io,
    const float* __restrict__ wbsc, const float* __restrict__ attno,
    const float* __restrict__ w0, const float* __restrict__ b0,
    const float* __restrict__ w1, const float* __restrict__ b1,
    const float* __restrict__ w2, const float* __restrict__ b2,
    const float* __restrict__ w3, const float* __restrict__ b3,
    const float* __restrict__ w4, const float* __restrict__ b4)
{
    constexpr int ROW = 72;                       // f16 per px row (144 B)
    __shared__ __align__(16) _Float16 LDS[4][64 * ROW];   // 36864 B
    const int tid  = threadIdx.x;
    const int wv   = tid >> 6;
    const int lane = tid & 63;
    const int nn   = lane & 15;
    const int quad = lane >> 4;
    _Float16* Wl = LDS[wv];                       // this wave's private region

    const int b   = blockIdx.x >> 10;             // 1024 blocks per image
    const int pix = (blockIdx.x * 256 + tid) & (HW - 1);
    float* base = io + b * 3 * HW + pix;

    // --- stage 0: load px, WB, CCM (ccm inline from mp attention output) ---
    const float s0 = wbsc[b * 4 + 0], s1 = wbsc[b * 4 + 1], s2 = wbsc[b * 4 + 2];
    float v0 = base[0] * s0;
    float v1 = base[HW] * s1;
    float v2 = base[2 * HW] * s2;
    const float* o2p = attno + b * 10;            // block-uniform -> scalar
    float I4[3];
    #pragma unroll
    for (int d = 0; d < 3; ++d) {
        float m0 = 0.1f * o2p[d * 3]     + (d == 0 ? 1.f : 0.f);
        float m1 = 0.1f * o2p[d * 3 + 1] + (d == 1 ? 1.f : 0.f);
        float m2 = 0.1f * o2p[d * 3 + 2] + (d == 2 ? 1.f : 0.f);
        I4[d] = fminf(fmaxf(m0 * v0 + m1 * v1 + m2 * v2, 1e-5f), 1.0f);
    }

    // --- stage 1: layer1 3->32 relu (VALU), write f16 row [px][k] ---
    #pragma unroll
    for (int j = 0; j < 32; j += 2) {
        float a0 = b0[j]   + w0[j*3]     * I4[0] + w0[j*3+1]     * I4[1] + w0[j*3+2]     * I4[2];
        float a1 = b0[j+1] + w0[(j+1)*3] * I4[0] + w0[(j+1)*3+1] * I4[1] + w0[(j+1)*3+2] * I4[2];
        f16x2 p;
        p[0] = (_Float16)fmaxf(a0, 0.f);
        p[1] = (_Float16)fmaxf(a1, 0.f);
        *(f16x2*)&Wl[lane * ROW + j] = p;
    }

    // --- resident weight B-frags + bias for layers 2-4 ---
    f16x8 wf[3][2];
    float bv[3][2];
    const float* wls[3] = { w1, w2, w3 };
    const float* bls[3] = { b1, b2, b3 };
    #pragma unroll
    for (int L = 0; L < 3; ++L) {
        #pragma unroll
        for (int h = 0; h < 2; ++h) {
            const float* wr = wls[L] + (16 * h + nn) * 32 + quad * 8;
            #pragma unroll
            for (int i = 0; i < 8; ++i) wf[L][h][i] = (_Float16)wr[i];
            bv[L][h] = bls[L][16 * h + nn];
        }
    }
    __syncthreads();

    // --- layers 2-4: MFMA + tanh, LDS round-trip per layer ---
    #pragma unroll
    for (int L = 0; L < 3; ++L) {
        f16x8 af[4];
        #pragma unroll
        for (int t = 0; t < 4; ++t)
            af[t] = *(const f16x8*)&Wl[(16 * t + nn) * ROW + quad * 8];
        __syncthreads();
        #pragma unroll
        for (int t = 0; t < 4; ++t) {
            #pragma unroll
            for (int h = 0; h < 2; ++h) {
                f32x4 c;
                c[0] = c[1] = c[2] = c[3] = bv[L][h];
                f32x4 d = __builtin_amdgcn_mfma_f32_16x16x32_f16(af[t], wf[L][h], c, 0, 0, 0);
                #pragma unroll
                for (int r = 0; r < 4; ++r)
                    Wl[(16 * t + quad * 4 + r) * ROW + 16 * h + nn] = (_Float16)tanh_fast(d[r]);
            }
        }
        __syncthreads();
    }

    // --- stage 5: layer5 32->3 (VALU) + residual + clip, in-place store ---
    float h4[32];
    #pragma unroll
    for (int g = 0; g < 4; ++g) {
        f16x8 rv = *(const f16x8*)&Wl[lane * ROW + g * 8];
        #pragma unroll
        for (int i = 0; i < 8; ++i) h4[g * 8 + i] = (float)rv[i];
    }
    #pragma unroll
    for (int d = 0; d < 3; ++d) {
        float a = b4[d];
        const float* wr = w4 + d * 32;            // uniform -> s_load
        #pragma unroll
        for (int k = 0; k < 32; ++k) a += h4[k] * wr[k];
        a += I4[d];
        base[d * HW] = fminf(fmaxf(a, 0.f), 1.0f);
    }
}

extern "C" void kernel_launch(void* const* d_in, const int* in_sizes, int n_in,
                              void* d_out, int out_size, void* d_ws, size_t ws_size,
                              hipStream_t stream)
{
    const float* I1      = (const float*)d_in[0];
    const float* kp_q    = (const float*)d_in[1];
    const float* kp_c1w  = (const float*)d_in[2];  const float* kp_c1b = (const float*)d_in[3];
    const float* kp_c2w  = (const float*)d_in[4];  const float* kp_c2b = (const float*)d_in[5];
    const float* kp_c3w  = (const float*)d_in[6];  const float* kp_c3b = (const float*)d_in[7];
    const float* kp_c4w  = (const float*)d_in[8];  const float* kp_c4b = (const float*)d_in[9];
    const float* kp_kw   = (const float*)d_in[10]; const float* kp_vw  = (const float*)d_in[11];
    const float* kp_pw   = (const float*)d_in[12]; const float* kp_dw  = (const float*)d_in[13];
    const float* kp_kb   = (const float*)d_in[14]; const float* kp_vb  = (const float*)d_in[15];
    const float* kp_pb   = (const float*)d_in[16]; const float* kp_db  = (const float*)d_in[17];
    const float* mp_q    = (const float*)d_in[18];
    const float* mp_c1w  = (const float*)d_in[19]; const float* mp_c1b = (const float*)d_in[20];
    const float* mp_c2w  = (const float*)d_in[21]; const float* mp_c2b = (const float*)d_in[22];
    const float* mp_c3w  = (const float*)d_in[23]; const float* mp_c3b = (const float*)d_in[24];
    const float* mp_c4w  = (const float*)d_in[25]; const float* mp_c4b = (const float*)d_in[26];
    const float* mp_kw   = (const float*)d_in[27]; const float* mp_vw  = (const float*)d_in[28];
    const float* mp_pw   = (const float*)d_in[29]; const float* mp_dw  = (const float*)d_in[30];
    const float* mp_kb   = (const float*)d_in[31]; const float* mp_vb  = (const float*)d_in[32];
    const float* mp_pb   = (const float*)d_in[33]; const float* mp_db  = (const float*)d_in[34];
    const float* gainb   = (const float*)d_in[35];
    const float* lw0 = (const float*)d_in[36]; const float* lb0 = (const float*)d_in[37];
    const float* lw1 = (const float*)d_in[38]; const float* lb1 = (const float*)d_in[39];
    const float* lw2 = (const float*)d_in[40]; const float* lb2 = (const float*)d_in[41];
    const float* lw3 = (const float*)d_in[42]; const float* lb3 = (const float*)d_in[43];
    const float* lw4 = (const float*)d_in[44]; const float* lb4 = (const float*)d_in[45];

    float* ws    = (float*)d_ws;
    float* ds1   = ws;                          // 8*8*256*256   = 4194304
    float* ds2   = ds1 + 8 * 8 * 256 * 256;     // 8*16*128*128  = 2097152
    float* ds3   = ds2 + 8 * 16 * 128 * 128;    // 8*32*64*64    = 1048576
    float* ds4   = ds3 + 8 * 32 * 64 * 64;      // 8*64*32*32    = 524288
    float* kbuf  = ds4 + 8 * 64 * 32 * 32;      // 524288
    float* vbuf  = kbuf + 8 * 64 * 1024;        // 524288
    float* attno = vbuf + 8 * 64 * 1024;        // 128 (kp: b*4+t / mp: b*10+t)
    float* sums  = attno + 128;                 // 32
    float* wbsc  = sums + 32;                   // 32
    float* I2    = (float*)d_out;               // I2 lives in d_out

    // --- Kernel_Predictor ---
    conv_s2<3, 512, true ><<<dim3(256, 2, BB), 256, 0, stream>>>(I1,  kp_c1w, kp_c1b, ds1);
    conv_s2<8, 256, true ><<<dim3(64,  4, BB), 256, 0, stream>>>(ds1, kp_c2w, kp_c2b, ds2);
    conv_s2<16, 128, true><<<dim3(16,  8, BB), 256, 0, stream>>>(ds2, kp_c3w, kp_c3b, ds3);
    conv_s2<32, 64, false><<<dim3(4,  16, BB), 256, 0, stream>>>(ds3, kp_c4w, kp_c4b, ds4);
    attn_kv_kernel<<<dim3(NTOK / 256, DIMC, BB), 256, 0, stream>>>(ds4, kp_kw, kp_kb, kp_vw, kp_vb, kbuf, vbuf);
    attn_head_kernel<<<BB * 4, 1024, 0, stream>>>(kbuf, vbuf, kp_q, kp_pw, kp_pb, kp_dw, kp_db, attno, 4);

    // --- gain + gaussian unsharp denoise -> I2 (in d_out); kp params inline ---
    denoise_kernel<<<(BB * 3 * HW / 2) / 256, 256, 0, stream>>>(I1, attno, gainb, I2);

    // --- Matrix_Predictor on I2 ---
    conv_s2<3, 512, true ><<<dim3(256, 2, BB), 256, 0, stream>>>(I2,  mp_c1w, mp_c1b, ds1);
    conv_s2<8, 256, true ><<<dim3(64,  4, BB), 256, 0, stream>>>(ds1, mp_c2w, mp_c2b, ds2);
    conv_s2<16, 128, true><<<dim3(16,  8, BB), 256, 0, stream>>>(ds2, mp_c3w, mp_c3b, ds3);
    conv_s2<32, 64, false><<<dim3(4,  16, BB), 256, 0, stream>>>(ds3, mp_c4w, mp_c4b, ds4);
    attn_kv_kernel<<<dim3(NTOK / 256, DIMC, BB), 256, 0, stream>>>(ds4, mp_kw, mp_kb, mp_vw, mp_vb, kbuf, vbuf);
    attn_head_kernel<<<BB * 10, 1024, 0, stream>>>(kbuf, vbuf, mp_q, mp_pw, mp_pb, mp_dw, mp_db, attno, 10);

    // --- shades-of-gray reduction (dist inline from attno) ---
    (void)hipMemsetAsync(sums, 0, 32 * sizeof(float), stream);
    wb_reduce_kernel<<<dim3(64, BB), 256, 0, stream>>>(I2, attno, sums);
    wb_finalize_kernel<<<1, 64, 0, stream>>>(sums, attno, wbsc);

    // --- fused WB + CCM + NILUT (in-place on d_out; ccm inline from attno) ---
    final_kernel<<<BB * HW / 256, 256, 0, stream>>>(I2, wbsc, attno,
        lw0, lb0, lw1, lb1, lw2, lb2, lw3, lb3, lw4, lb4);
}

// Round 6
// 438.863 us; speedup vs baseline: 3.0105x; 1.0458x over previous
//
#include <hip/hip_runtime.h>
#include <math.h>

// ---------------------------------------------------------------------------
// Input_level_Adapeter pipeline, round 6: dispatch-count attack (17 -> 12).
//  - attn_kv eliminated: score = (q.kw).dx + q.kb ; o = vw.(sum a*dx)/S + vb
//    (K,V never materialized; fused into attn_kernel on ds4 directly)
//  - denoise fused into conv1_mp: thread computes its 3x3 I2 patch from a
//    5x5 I1 patch, writes its owned 2x2 I2 block, zero-masks conv edges
//  - wb: chunked partial sums (no atomics/memset); wbsc rebuilt in final
//  - conv1/conv2: OCTILE=8; conv3/4: OCTILE=4
//  - final_kernel MFMA core unchanged (93 us, near tanh floor)
// d_out doubles as the I2 buffer.
// ---------------------------------------------------------------------------

#define BN_MUL 0.9999950000374997f   // 1/sqrt(1+1e-5)

static constexpr int BB   = 8;
static constexpr int HH   = 512;
static constexpr int WW   = 512;
static constexpr int HW   = HH * WW;
static constexpr int NTOK = 1024;    // (512/16)^2
static constexpr int DIMC = 64;
static constexpr int WBCH = 32;      // wb_reduce chunks per (b,c)

typedef _Float16 f16x8 __attribute__((ext_vector_type(8)));
typedef _Float16 f16x2 __attribute__((ext_vector_type(2)));
typedef float    f32x4 __attribute__((ext_vector_type(4)));

__device__ __forceinline__ float gelu_exact(float x) {
    return 0.5f * x * (1.0f + erff(x * 0.7071067811865476f));
}

// branch-free fast tanh: 1 - 2/(e^{2x}+1)
__device__ __forceinline__ float tanh_fast(float x) {
    float e = __expf(2.0f * x);
    return 1.0f - 2.0f * __builtin_amdgcn_rcpf(e + 1.0f);
}

// --- stride-2 3x3 conv + bias + BN (+ optional exact GELU), zero padding ---
// grid: (Hout*Wout/256, Cout/OCT, B). oc uniform per block -> scalar weights.
template<int Cin, int Hin, int OCT, bool GELU>
__global__ __launch_bounds__(256) void conv_s2(const float* __restrict__ in,
                                               const float* __restrict__ wt,
                                               const float* __restrict__ bs,
                                               float* __restrict__ out)
{
    constexpr int Win  = Hin, Hout = Hin / 2, Wout = Hin / 2;
    constexpr int WSH  = (Wout == 256) ? 8 : (Wout == 128) ? 7 : (Wout == 64) ? 6 : 5;
    constexpr int PLANE = Hout * Wout;

    const int sp  = blockIdx.x * 256 + threadIdx.x;
    const int ow  = sp & (Wout - 1);
    const int oh  = sp >> WSH;
    const int oc0 = blockIdx.y * OCT;
    const int b   = blockIdx.z;
    const int Cout = (int)gridDim.y * OCT;

    float acc[OCT];
    #pragma unroll
    for (int o = 0; o < OCT; ++o) acc[o] = bs[oc0 + o];

    const int ih0 = oh * 2 - 1, iw0 = ow * 2 - 1;
    const float fh0 = (ih0 >= 0) ? 1.f : 0.f;
    const float fw0 = (iw0 >= 0) ? 1.f : 0.f;
    const int r0 = (ih0 >= 0) ? ih0 : 0;
    const int cc0 = (iw0 >= 0) ? iw0 : 0;

    const float* ip = in + (size_t)(b * Cin) * Hin * Win;
    #pragma unroll
    for (int ic = 0; ic < Cin; ++ic) {
        const float* pl = ip + ic * Hin * Win;
        const float* p0 = pl + r0 * Win;
        const float* p1 = pl + (ih0 + 1) * Win;
        const float* p2 = pl + (ih0 + 2) * Win;
        float  v00 = p0[cc0] * (fh0 * fw0);
        float2 va  = *(const float2*)(p0 + iw0 + 1);
        float  v01 = va.x * fh0, v02 = va.y * fh0;
        float  v10 = p1[cc0] * fw0;
        float2 vb  = *(const float2*)(p1 + iw0 + 1);
        float  v20 = p2[cc0] * fw0;
        float2 vc  = *(const float2*)(p2 + iw0 + 1);
        #pragma unroll
        for (int o = 0; o < OCT; ++o) {
            const float* wr = wt + ((oc0 + o) * Cin + ic) * 9;   // uniform -> s_load
            acc[o] += v00 * wr[0] + v01 * wr[1] + v02 * wr[2]
                    + v10 * wr[3] + vb.x * wr[4] + vb.y * wr[5]
                    + v20 * wr[6] + vc.x * wr[7] + vc.y * wr[8];
        }
    }
    #pragma unroll
    for (int o = 0; o < OCT; ++o) {
        float a = acc[o] * BN_MUL;
        if (GELU) a = gelu_exact(a);
        out[(b * Cout + oc0 + o) * PLANE + sp] = a;
    }
}

// --- fused denoise + conv1_mp (3ch I1 -> I2 write + 8ch conv out) ---
// grid (256, 1, 8), 256 thr; thread owns conv-out (oh,ow) and the 2x2 I2
// block rows 2oh..2oh+1, cols 2ow..2ow+1. blur = reflect-pad gaussian.
__global__ __launch_bounds__(256) void denoise_conv1_kernel(
    const float* __restrict__ I1, const float* __restrict__ attno,
    const float* __restrict__ gain_base,
    const float* __restrict__ wt, const float* __restrict__ bs,
    float* __restrict__ I2, float* __restrict__ out)
{
    const int sp = blockIdx.x * 256 + threadIdx.x;
    const int ow = sp & 255;
    const int oh = sp >> 8;
    const int b  = blockIdx.z;

    // kp params (b block-uniform -> scalar math)
    const float o0 = attno[b * 4 + 0], o1 = attno[b * 4 + 1];
    const float o2 = attno[b * 4 + 2], o3 = attno[b * 4 + 3];
    const float r1 = 0.1f * o0 + 3.0f;
    const float r2 = 0.1f * o1 + 2.0f;
    const float g  = o2 + gain_base[0];
    const float sg = 1.0f / (1.0f + __expf(-o3));
    const float ex = __expf(-0.5f / (r1 * r1));
    const float nx = 1.0f / (2.0f * ex + 1.0f);
    const float ey = __expf(-0.5f / (r2 * r2));
    const float ny = 1.0f / (2.0f * ey + 1.0f);
    const float kx0 = ex * nx, kx1 = nx;
    const float ky0 = ey * ny, ky1 = ny;

    const int rbase = 2 * oh - 2, cbase = 2 * ow - 2;
    int ri[5], ci[5];
    #pragma unroll
    for (int i = 0; i < 5; ++i) {
        int r = rbase + i; ri[i] = r < 0 ? -r : (r > 511 ? 1022 - r : r);
        int c = cbase + i; ci[i] = c < 0 ? -c : (c > 511 ? 1022 - c : c);
    }
    const bool topE = (oh == 0), leftE = (ow == 0);

    float acc[8];
    #pragma unroll
    for (int o = 0; o < 8; ++o) acc[o] = bs[o];

    #pragma unroll
    for (int c = 0; c < 3; ++c) {
        const float* ip = I1 + ((size_t)b * 3 + c) * HW;
        float p[5][5];
        #pragma unroll
        for (int i = 0; i < 5; ++i) {
            const float* rp = ip + ri[i] * WW;
            #pragma unroll
            for (int j = 0; j < 5; ++j) p[i][j] = rp[ci[j]];
        }
        float hs[5][3];
        #pragma unroll
        for (int i = 0; i < 5; ++i)
            #pragma unroll
            for (int j = 0; j < 3; ++j)
                hs[i][j] = kx0 * (p[i][j] + p[i][j + 2]) + kx1 * p[i][j + 1];
        float w2[3][3];
        #pragma unroll
        for (int i = 0; i < 3; ++i)
            #pragma unroll
            for (int j = 0; j < 3; ++j) {
                float bl = g * (ky0 * (hs[i][j] + hs[i + 2][j]) + ky1 * hs[i + 1][j]);
                float val = bl + sg * (p[i + 1][j + 1] - bl);
                w2[i][j] = fminf(fmaxf(val, 1e-5f), 1.0f);
            }
        // write owned 2x2 I2 block (rows 2oh,2oh+1; cols 2ow,2ow+1)
        float* op = I2 + ((size_t)b * 3 + c) * HW + (2 * oh) * WW + 2 * ow;
        float2 w0v; w0v.x = w2[1][1]; w0v.y = w2[1][2];
        float2 w1v; w1v.x = w2[2][1]; w1v.y = w2[2][2];
        *(float2*)op        = w0v;
        *(float2*)(op + WW) = w1v;
        // zero-pad mask for the conv (row -1 / col -1)
        if (topE)  { w2[0][0] = 0.f; w2[0][1] = 0.f; w2[0][2] = 0.f; }
        if (leftE) { w2[0][0] = 0.f; w2[1][0] = 0.f; w2[2][0] = 0.f; }
        #pragma unroll
        for (int o = 0; o < 8; ++o) {
            const float* wr = wt + (o * 3 + c) * 9;          // uniform -> s_load
            acc[o] += w2[0][0] * wr[0] + w2[0][1] * wr[1] + w2[0][2] * wr[2]
                    + w2[1][0] * wr[3] + w2[1][1] * wr[4] + w2[1][2] * wr[5]
                    + w2[2][0] * wr[6] + w2[2][1] * wr[7] + w2[2][2] * wr[8];
        }
    }
    #pragma unroll
    for (int o = 0; o < 8; ++o)
        out[(b * 8 + o) * 65536 + sp] = gelu_exact(acc[o] * BN_MUL);
}

// --- fused attention: K,V folded away. One block per (b,t), 1024 threads ---
// score_n = 0.125*( (q.kw).dx_n + q.kb ); o = vw.(sum a_n dx_n)/S + vb; proj.
__global__ __launch_bounds__(1024) void attn_kernel(
    const float* __restrict__ dx, const float* __restrict__ q,
    const float* __restrict__ kw, const float* __restrict__ kb,
    const float* __restrict__ vw, const float* __restrict__ vb,
    const float* __restrict__ pw, const float* __restrict__ pb,
    const float* __restrict__ dw, const float* __restrict__ db,
    float* __restrict__ outv, int T)
{
    __shared__ float qk[DIMC];
    __shared__ float red[1024];
    __shared__ float sc[NTOK];
    __shared__ float uN[DIMC];
    __shared__ float osh[DIMC];
    __shared__ float psh[DIMC];
    __shared__ float qkb_s;
    const int tid = threadIdx.x;
    const int bt  = blockIdx.x;
    const int b = bt / T, t = bt - b * T;
    const float* qt = q + t * DIMC;

    if (tid < DIMC) {
        float s = 0.f;
        #pragma unroll
        for (int c = 0; c < DIMC; ++c) s += qt[c] * kw[c * DIMC + tid];
        qk[tid] = s;
    }
    if (tid == 1023) {
        float s = 0.f;
        #pragma unroll
        for (int c = 0; c < DIMC; ++c) s += qt[c] * kb[c];
        qkb_s = s;
    }
    __syncthreads();

    const float* dp = dx + (size_t)(b * DIMC) * NTOK;
    float s = qkb_s;
    #pragma unroll
    for (int c = 0; c < DIMC; ++c) s += qk[c] * dp[c * NTOK + tid];
    s *= 0.125f;                       // 64^-0.5

    red[tid] = s;
    __syncthreads();
    for (int off = 512; off > 0; off >>= 1) {
        if (tid < off) red[tid] = fmaxf(red[tid], red[tid + off]);
        __syncthreads();
    }
    float m = red[0];
    __syncthreads();

    float e = __expf(s - m);
    sc[tid] = e;
    red[tid] = e;
    __syncthreads();
    for (int off = 512; off > 0; off >>= 1) {
        if (tid < off) red[tid] += red[tid + off];
        __syncthreads();
    }
    float Ssum = red[0];
    __syncthreads();

    // u[c] = sum_n e_n * dx[c][n]; 16-way split over n
    const int c  = tid & 63, qq = tid >> 6;
    float part = 0.f;
    const float* dr = dp + c * NTOK + qq * 64;
    const float* sr = sc + qq * 64;
    #pragma unroll
    for (int n = 0; n < 64; ++n) part += sr[n] * dr[n];
    red[tid] = part;
    __syncthreads();
    if (tid < DIMC) {
        float u = 0.f;
        #pragma unroll
        for (int k = 0; k < 16; ++k) u += red[tid + k * 64];
        uN[tid] = u / Ssum;
    }
    __syncthreads();
    if (tid < DIMC) {
        float o = vb[tid];
        const float* vr = vw + tid * DIMC;
        #pragma unroll
        for (int cc = 0; cc < DIMC; ++cc) o += vr[cc] * uN[cc];
        osh[tid] = o;
    }
    __syncthreads();
    if (tid < DIMC) {
        float p = pb[tid];
        const float* pr = pw + tid * DIMC;
        #pragma unroll
        for (int cc = 0; cc < DIMC; ++cc) p += pr[cc] * osh[cc];
        psh[tid] = p;
    }
    __syncthreads();
    if (tid == 0) {
        float r = db[0];
        #pragma unroll
        for (int cc = 0; cc < DIMC; ++cc) r += psh[cc] * dw[cc];
        outv[bt] = r;
    }
}

// --- chunked sum of I2^dist per (b,c): grid (WBCH, 24), no atomics/memset ---
__global__ __launch_bounds__(256) void wb_reduce_kernel(const float* __restrict__ I2,
                                                        const float* __restrict__ attno,
                                                        float* __restrict__ part)
{
    __shared__ float red[256];
    const int bc = blockIdx.y;                 // b*3 + c
    const int b  = bc / 3;
    float d = attno[b * 10 + 9];
    d = fmaxf(d, 0.f) + 1.0f;
    constexpr int CHUNK = HW / WBCH;           // 8192 px
    const float4* base = (const float4*)(I2 + (size_t)bc * HW + blockIdx.x * CHUNK);
    float l = 0.f;
    #pragma unroll
    for (int i = threadIdx.x, it = 0; it < CHUNK / 4 / 256; ++it, i += 256) {
        float4 v = base[i];
        l += __expf(d * __logf(v.x)) + __expf(d * __logf(v.y))
           + __expf(d * __logf(v.z)) + __expf(d * __logf(v.w));
    }
    red[threadIdx.x] = l;
    __syncthreads();
    for (int off = 128; off > 0; off >>= 1) {
        if (threadIdx.x < off) red[threadIdx.x] += red[threadIdx.x + off];
        __syncthreads();
    }
    if (threadIdx.x == 0) part[bc * WBCH + blockIdx.x] = red[0];
}

// --- fused WB + CCM + NILUT: layers 2-4 on MFMA f16, in-place on d_out ---
// wbsc rebuilt per block from wb partials (scalar loads, block-uniform).
__global__ void __launch_bounds__(256) final_kernel(
    float* __restrict__ io,
    const float* __restrict__ part, const float* __restrict__ attno,
    const float* __restrict__ w0, const float* __restrict__ b0,
    const float* __restrict__ w1, const float* __restrict__ b1,
    const float* __restrict__ w2, const float* __restrict__ b2,
    const float* __restrict__ w3, const float* __restrict__ b3,
    const float* __restrict__ w4, const float* __restrict__ b4)
{
    constexpr int ROW = 72;                       // f16 per px row (144 B)
    __shared__ __align__(16) _Float16 LDS[4][64 * ROW];   // 36864 B
    const int tid  = threadIdx.x;
    const int wv   = tid >> 6;
    const int lane = tid & 63;
    const int nn   = lane & 15;
    const int quad = lane >> 4;
    _Float16* Wl = LDS[wv];

    const int b   = blockIdx.x >> 10;             // 1024 blocks per image
    const int pix = (blockIdx.x * 256 + tid) & (HW - 1);
    float* base = io + b * 3 * HW + pix;

    // --- wbsc from partials (block-uniform -> scalar) ---
    const float* o2p = attno + b * 10;
    float dd = fmaxf(o2p[9], 0.f) + 1.0f;
    float inv = 1.0f / dd;
    float s[3];
    #pragma unroll
    for (int c = 0; c < 3; ++c) {
        float t0 = 0.f;
        const float* pp = part + (b * 3 + c) * WBCH;
        #pragma unroll
        for (int k = 0; k < WBCH; ++k) t0 += pp[k];
        s[c] = t0;
    }
    const float avg = __expf(inv * __logf((s[0] + s[1] + s[2]) * (1.0f / (3.0f * HW))));
    const float wb0 = avg / __expf(inv * __logf(s[0] * (1.0f / HW)));
    const float wb1 = avg / __expf(inv * __logf(s[1] * (1.0f / HW)));
    const float wb2 = avg / __expf(inv * __logf(s[2] * (1.0f / HW)));

    // --- stage 0: load px, WB, CCM (ccm inline from mp attention output) ---
    float v0 = base[0] * wb0;
    float v1 = base[HW] * wb1;
    float v2 = base[2 * HW] * wb2;
    float I4[3];
    #pragma unroll
    for (int d = 0; d < 3; ++d) {
        float m0 = 0.1f * o2p[d * 3]     + (d == 0 ? 1.f : 0.f);
        float m1 = 0.1f * o2p[d * 3 + 1] + (d == 1 ? 1.f : 0.f);
        float m2 = 0.1f * o2p[d * 3 + 2] + (d == 2 ? 1.f : 0.f);
        I4[d] = fminf(fmaxf(m0 * v0 + m1 * v1 + m2 * v2, 1e-5f), 1.0f);
    }

    // --- stage 1: layer1 3->32 relu (VALU), write f16 row [px][k] ---
    #pragma unroll
    for (int j = 0; j < 32; j += 2) {
        float a0 = b0[j]   + w0[j*3]     * I4[0] + w0[j*3+1]     * I4[1] + w0[j*3+2]     * I4[2];
        float a1 = b0[j+1] + w0[(j+1)*3] * I4[0] + w0[(j+1)*3+1] * I4[1] + w0[(j+1)*3+2] * I4[2];
        f16x2 p;
        p[0] = (_Float16)fmaxf(a0, 0.f);
        p[1] = (_Float16)fmaxf(a1, 0.f);
        *(f16x2*)&Wl[lane * ROW + j] = p;
    }

    // --- resident weight B-frags + bias for layers 2-4 ---
    f16x8 wf[3][2];
    float bv[3][2];
    const float* wls[3] = { w1, w2, w3 };
    const float* bls[3] = { b1, b2, b3 };
    #pragma unroll
    for (int L = 0; L < 3; ++L) {
        #pragma unroll
        for (int h = 0; h < 2; ++h) {
            const float* wr = wls[L] + (16 * h + nn) * 32 + quad * 8;
            #pragma unroll
            for (int i = 0; i < 8; ++i) wf[L][h][i] = (_Float16)wr[i];
            bv[L][h] = bls[L][16 * h + nn];
        }
    }
    __syncthreads();

    // --- layers 2-4: MFMA + tanh, LDS round-trip per layer ---
    #pragma unroll
    for (int L = 0; L < 3; ++L) {
        f16x8 af[4];
        #pragma unroll
        for (int t = 0; t < 4; ++t)
            af[t] = *(const f16x8*)&Wl[(16 * t + nn) * ROW + quad * 8];
        __syncthreads();
        #pragma unroll
        for (int t = 0; t < 4; ++t) {
            #pragma unroll
            for (int h = 0; h < 2; ++h) {
                f32x4 c;
                c[0] = c[1] = c[2] = c[3] = bv[L][h];
                f32x4 d = __builtin_amdgcn_mfma_f32_16x16x32_f16(af[t], wf[L][h], c, 0, 0, 0);
                #pragma unroll
                for (int r = 0; r < 4; ++r)
                    Wl[(16 * t + quad * 4 + r) * ROW + 16 * h + nn] = (_Float16)tanh_fast(d[r]);
            }
        }
        __syncthreads();
    }

    // --- stage 5: layer5 32->3 (VALU) + residual + clip, in-place store ---
    float h4[32];
    #pragma unroll
    for (int g = 0; g < 4; ++g) {
        f16x8 rv = *(const f16x8*)&Wl[lane * ROW + g * 8];
        #pragma unroll
        for (int i = 0; i < 8; ++i) h4[g * 8 + i] = (float)rv[i];
    }
    #pragma unroll
    for (int d = 0; d < 3; ++d) {
        float a = b4[d];
        const float* wr = w4 + d * 32;            // uniform -> s_load
        #pragma unroll
        for (int k = 0; k < 32; ++k) a += h4[k] * wr[k];
        a += I4[d];
        base[d * HW] = fminf(fmaxf(a, 0.f), 1.0f);
    }
}

extern "C" void kernel_launch(void* const* d_in, const int* in_sizes, int n_in,
                              void* d_out, int out_size, void* d_ws, size_t ws_size,
                              hipStream_t stream)
{
    const float* I1      = (const float*)d_in[0];
    const float* kp_q    = (const float*)d_in[1];
    const float* kp_c1w  = (const float*)d_in[2];  const float* kp_c1b = (const float*)d_in[3];
    const float* kp_c2w  = (const float*)d_in[4];  const float* kp_c2b = (const float*)d_in[5];
    const float* kp_c3w  = (const float*)d_in[6];  const float* kp_c3b = (const float*)d_in[7];
    const float* kp_c4w  = (const float*)d_in[8];  const float* kp_c4b = (const float*)d_in[9];
    const float* kp_kw   = (const float*)d_in[10]; const float* kp_vw  = (const float*)d_in[11];
    const float* kp_pw   = (const float*)d_in[12]; const float* kp_dw  = (const float*)d_in[13];
    const float* kp_kb   = (const float*)d_in[14]; const float* kp_vb  = (const float*)d_in[15];
    const float* kp_pb   = (const float*)d_in[16]; const float* kp_db  = (const float*)d_in[17];
    const float* mp_q    = (const float*)d_in[18];
    const float* mp_c1w  = (const float*)d_in[19]; const float* mp_c1b = (const float*)d_in[20];
    const float* mp_c2w  = (const float*)d_in[21]; const float* mp_c2b = (const float*)d_in[22];
    const float* mp_c3w  = (const float*)d_in[23]; const float* mp_c3b = (const float*)d_in[24];
    const float* mp_c4w  = (const float*)d_in[25]; const float* mp_c4b = (const float*)d_in[26];
    const float* mp_kw   = (const float*)d_in[27]; const float* mp_vw  = (const float*)d_in[28];
    const float* mp_pw   = (const float*)d_in[29]; const float* mp_dw  = (const float*)d_in[30];
    const float* mp_kb   = (const float*)d_in[31]; const float* mp_vb  = (const float*)d_in[32];
    const float* mp_pb   = (const float*)d_in[33]; const float* mp_db  = (const float*)d_in[34];
    const float* gainb   = (const float*)d_in[35];
    const float* lw0 = (const float*)d_in[36]; const float* lb0 = (const float*)d_in[37];
    const float* lw1 = (const float*)d_in[38]; const float* lb1 = (const float*)d_in[39];
    const float* lw2 = (const float*)d_in[40]; const float* lb2 = (const float*)d_in[41];
    const float* lw3 = (const float*)d_in[42]; const float* lb3 = (const float*)d_in[43];
    const float* lw4 = (const float*)d_in[44]; const float* lb4 = (const float*)d_in[45];

    float* ws    = (float*)d_ws;
    float* ds1   = ws;                          // 8*8*256*256   = 4194304
    float* ds2   = ds1 + 8 * 8 * 256 * 256;     // 8*16*128*128  = 2097152
    float* ds3   = ds2 + 8 * 16 * 128 * 128;    // 8*32*64*64    = 1048576
    float* ds4   = ds3 + 8 * 32 * 64 * 64;      // 8*64*32*32    = 524288
    float* attno = ds4 + 8 * 64 * 32 * 32;      // 128 (kp: b*4+t / mp: b*10+t)
    float* part  = attno + 128;                 // 24 * WBCH
    float* I2    = (float*)d_out;               // I2 lives in d_out

    // --- Kernel_Predictor ---
    conv_s2<3, 512, 8, true ><<<dim3(256, 1, BB), 256, 0, stream>>>(I1,  kp_c1w, kp_c1b, ds1);
    conv_s2<8, 256, 8, true ><<<dim3(64,  2, BB), 256, 0, stream>>>(ds1, kp_c2w, kp_c2b, ds2);
    conv_s2<16, 128, 4, true><<<dim3(16,  8, BB), 256, 0, stream>>>(ds2, kp_c3w, kp_c3b, ds3);
    conv_s2<32, 64, 4, false><<<dim3(4,  16, BB), 256, 0, stream>>>(ds3, kp_c4w, kp_c4b, ds4);
    attn_kernel<<<BB * 4, 1024, 0, stream>>>(ds4, kp_q, kp_kw, kp_kb, kp_vw, kp_vb,
                                             kp_pw, kp_pb, kp_dw, kp_db, attno, 4);

    // --- denoise fused with conv1_mp: writes I2 (d_out) + ds1 ---
    denoise_conv1_kernel<<<dim3(256, 1, BB), 256, 0, stream>>>(I1, attno, gainb,
                                                               mp_c1w, mp_c1b, I2, ds1);

    // --- rest of Matrix_Predictor ---
    conv_s2<8, 256, 8, true ><<<dim3(64,  2, BB), 256, 0, stream>>>(ds1, mp_c2w, mp_c2b, ds2);
    conv_s2<16, 128, 4, true><<<dim3(16,  8, BB), 256, 0, stream>>>(ds2, mp_c3w, mp_c3b, ds3);
    conv_s2<32, 64, 4, false><<<dim3(4,  16, BB), 256, 0, stream>>>(ds3, mp_c4w, mp_c4b, ds4);
    attn_kernel<<<BB * 10, 1024, 0, stream>>>(ds4, mp_q, mp_kw, mp_kb, mp_vw, mp_vb,
                                              mp_pw, mp_pb, mp_dw, mp_db, attno, 10);

    // --- shades-of-gray partial sums (no atomics, no memset) ---
    wb_reduce_kernel<<<dim3(WBCH, 24), 256, 0, stream>>>(I2, attno, part);

    // --- fused WB + CCM + NILUT (in-place on d_out) ---
    final_kernel<<<BB * HW / 256, 256, 0, stream>>>(I2, part, attno,
        lw0, lb0, lw1, lb1, lw2, lb2, lw3, lb3, lw4, lb4);
}

// Round 10
// 432.689 us; speedup vs baseline: 3.0535x; 1.0143x over previous
//
#include <hip/hip_runtime.h>
#include <math.h>

// ---------------------------------------------------------------------------
// Input_level_Adapeter pipeline, round 10 (environment-vs-conv_s2q test):
//  - conv_s2q REMOVED. All convs = round-6 conv_s2 (passed, 439 us).
//  - attn / denoise_conv1 / wb_reduce = round 6 verbatim (passed).
//  - final_kernel = round-5 form reading precomputed wbsc (passed, 92.8 us)
//    + trivial part->wbsc wb_finalize kernel (fixes r6's 10 us final regress).
// If this aborts, the container is poisoned (r7 crash residue) -> resubmit r6.
// d_out doubles as the I2 buffer.
// ---------------------------------------------------------------------------

#define BN_MUL 0.9999950000374997f   // 1/sqrt(1+1e-5)

static constexpr int BB   = 8;
static constexpr int HH   = 512;
static constexpr int WW   = 512;
static constexpr int HW   = HH * WW;
static constexpr int NTOK = 1024;    // (512/16)^2
static constexpr int DIMC = 64;
static constexpr int WBCH = 32;      // wb_reduce chunks per (b,c)

typedef _Float16 f16x8 __attribute__((ext_vector_type(8)));
typedef _Float16 f16x2 __attribute__((ext_vector_type(2)));
typedef float    f32x4 __attribute__((ext_vector_type(4)));

__device__ __forceinline__ float gelu_exact(float x) {
    return 0.5f * x * (1.0f + erff(x * 0.7071067811865476f));
}

// branch-free fast tanh: 1 - 2/(e^{2x}+1)
__device__ __forceinline__ float tanh_fast(float x) {
    float e = __expf(2.0f * x);
    return 1.0f - 2.0f * __builtin_amdgcn_rcpf(e + 1.0f);
}

// --- stride-2 3x3 conv + bias + BN (+ optional exact GELU), zero padding ---
// [round 6 verbatim] grid: (Hout*Wout/256, Cout/OCT, B).
template<int Cin, int Hin, int OCT, bool GELU>
__global__ __launch_bounds__(256) void conv_s2(const float* __restrict__ in,
                                               const float* __restrict__ wt,
                                               const float* __restrict__ bs,
                                               float* __restrict__ out)
{
    constexpr int Win  = Hin, Hout = Hin / 2, Wout = Hin / 2;
    constexpr int WSH  = (Wout == 256) ? 8 : (Wout == 128) ? 7 : (Wout == 64) ? 6 : 5;
    constexpr int PLANE = Hout * Wout;

    const int sp  = blockIdx.x * 256 + threadIdx.x;
    const int ow  = sp & (Wout - 1);
    const int oh  = sp >> WSH;
    const int oc0 = blockIdx.y * OCT;
    const int b   = blockIdx.z;
    const int Cout = (int)gridDim.y * OCT;

    float acc[OCT];
    #pragma unroll
    for (int o = 0; o < OCT; ++o) acc[o] = bs[oc0 + o];

    const int ih0 = oh * 2 - 1, iw0 = ow * 2 - 1;
    const float fh0 = (ih0 >= 0) ? 1.f : 0.f;
    const float fw0 = (iw0 >= 0) ? 1.f : 0.f;
    const int r0 = (ih0 >= 0) ? ih0 : 0;
    const int cc0 = (iw0 >= 0) ? iw0 : 0;

    const float* ip = in + (size_t)(b * Cin) * Hin * Win;
    #pragma unroll
    for (int ic = 0; ic < Cin; ++ic) {
        const float* pl = ip + ic * Hin * Win;
        const float* p0 = pl + r0 * Win;
        const float* p1 = pl + (ih0 + 1) * Win;
        const float* p2 = pl + (ih0 + 2) * Win;
        float  v00 = p0[cc0] * (fh0 * fw0);
        float2 va  = *(const float2*)(p0 + iw0 + 1);
        float  v01 = va.x * fh0, v02 = va.y * fh0;
        float  v10 = p1[cc0] * fw0;
        float2 vb  = *(const float2*)(p1 + iw0 + 1);
        float  v20 = p2[cc0] * fw0;
        float2 vc  = *(const float2*)(p2 + iw0 + 1);
        #pragma unroll
        for (int o = 0; o < OCT; ++o) {
            const float* wr = wt + ((oc0 + o) * Cin + ic) * 9;   // uniform -> s_load
            acc[o] += v00 * wr[0] + v01 * wr[1] + v02 * wr[2]
                    + v10 * wr[3] + vb.x * wr[4] + vb.y * wr[5]
                    + v20 * wr[6] + vc.x * wr[7] + vc.y * wr[8];
        }
    }
    #pragma unroll
    for (int o = 0; o < OCT; ++o) {
        float a = acc[o] * BN_MUL;
        if (GELU) a = gelu_exact(a);
        out[(size_t)(b * Cout + oc0 + o) * PLANE + sp] = a;
    }
}

// --- fused denoise + conv1_mp --- [round 6 verbatim]
__global__ __launch_bounds__(256) void denoise_conv1_kernel(
    const float* __restrict__ I1, const float* __restrict__ attno,
    const float* __restrict__ gain_base,
    const float* __restrict__ wt, const float* __restrict__ bs,
    float* __restrict__ I2, float* __restrict__ out)
{
    const int sp = blockIdx.x * 256 + threadIdx.x;
    const int ow = sp & 255;
    const int oh = sp >> 8;
    const int b  = blockIdx.z;

    const float o0 = attno[b * 4 + 0], o1 = attno[b * 4 + 1];
    const float o2 = attno[b * 4 + 2], o3 = attno[b * 4 + 3];
    const float r1 = 0.1f * o0 + 3.0f;
    const float r2 = 0.1f * o1 + 2.0f;
    const float g  = o2 + gain_base[0];
    const float sg = 1.0f / (1.0f + __expf(-o3));
    const float ex = __expf(-0.5f / (r1 * r1));
    const float nx = 1.0f / (2.0f * ex + 1.0f);
    const float ey = __expf(-0.5f / (r2 * r2));
    const float ny = 1.0f / (2.0f * ey + 1.0f);
    const float kx0 = ex * nx, kx1 = nx;
    const float ky0 = ey * ny, ky1 = ny;

    const int rbase = 2 * oh - 2, cbase = 2 * ow - 2;
    int ri[5], ci[5];
    #pragma unroll
    for (int i = 0; i < 5; ++i) {
        int r = rbase + i; ri[i] = r < 0 ? -r : (r > 511 ? 1022 - r : r);
        int c = cbase + i; ci[i] = c < 0 ? -c : (c > 511 ? 1022 - c : c);
    }
    const bool topE = (oh == 0), leftE = (ow == 0);

    float acc[8];
    #pragma unroll
    for (int o = 0; o < 8; ++o) acc[o] = bs[o];

    #pragma unroll
    for (int c = 0; c < 3; ++c) {
        const float* ip = I1 + ((size_t)b * 3 + c) * HW;
        float p[5][5];
        #pragma unroll
        for (int i = 0; i < 5; ++i) {
            const float* rp = ip + ri[i] * WW;
            #pragma unroll
            for (int j = 0; j < 5; ++j) p[i][j] = rp[ci[j]];
        }
        float hs[5][3];
        #pragma unroll
        for (int i = 0; i < 5; ++i)
            #pragma unroll
            for (int j = 0; j < 3; ++j)
                hs[i][j] = kx0 * (p[i][j] + p[i][j + 2]) + kx1 * p[i][j + 1];
        float w2[3][3];
        #pragma unroll
        for (int i = 0; i < 3; ++i)
            #pragma unroll
            for (int j = 0; j < 3; ++j) {
                float bl = g * (ky0 * (hs[i][j] + hs[i + 2][j]) + ky1 * hs[i + 1][j]);
                float val = bl + sg * (p[i + 1][j + 1] - bl);
                w2[i][j] = fminf(fmaxf(val, 1e-5f), 1.0f);
            }
        float* op = I2 + ((size_t)b * 3 + c) * HW + (2 * oh) * WW + 2 * ow;
        float2 w0v; w0v.x = w2[1][1]; w0v.y = w2[1][2];
        float2 w1v; w1v.x = w2[2][1]; w1v.y = w2[2][2];
        *(float2*)op        = w0v;
        *(float2*)(op + WW) = w1v;
        if (topE)  { w2[0][0] = 0.f; w2[0][1] = 0.f; w2[0][2] = 0.f; }
        if (leftE) { w2[0][0] = 0.f; w2[1][0] = 0.f; w2[2][0] = 0.f; }
        #pragma unroll
        for (int o = 0; o < 8; ++o) {
            const float* wr = wt + (o * 3 + c) * 9;          // uniform -> s_load
            acc[o] += w2[0][0] * wr[0] + w2[0][1] * wr[1] + w2[0][2] * wr[2]
                    + w2[1][0] * wr[3] + w2[1][1] * wr[4] + w2[1][2] * wr[5]
                    + w2[2][0] * wr[6] + w2[2][1] * wr[7] + w2[2][2] * wr[8];
        }
    }
    #pragma unroll
    for (int o = 0; o < 8; ++o)
        out[(b * 8 + o) * 65536 + sp] = gelu_exact(acc[o] * BN_MUL);
}

// --- fused attention (K,V folded) --- [round 6 verbatim]
__global__ __launch_bounds__(1024) void attn_kernel(
    const float* __restrict__ dx, const float* __restrict__ q,
    const float* __restrict__ kw, const float* __restrict__ kb,
    const float* __restrict__ vw, const float* __restrict__ vb,
    const float* __restrict__ pw, const float* __restrict__ pb,
    const float* __restrict__ dw, const float* __restrict__ db,
    float* __restrict__ outv, int T)
{
    __shared__ float qk[DIMC];
    __shared__ float red[1024];
    __shared__ float sc[NTOK];
    __shared__ float uN[DIMC];
    __shared__ float osh[DIMC];
    __shared__ float psh[DIMC];
    __shared__ float qkb_s;
    const int tid = threadIdx.x;
    const int bt  = blockIdx.x;
    const int b = bt / T, t = bt - b * T;
    const float* qt = q + t * DIMC;

    if (tid < DIMC) {
        float s = 0.f;
        #pragma unroll
        for (int c = 0; c < DIMC; ++c) s += qt[c] * kw[c * DIMC + tid];
        qk[tid] = s;
    }
    if (tid == 1023) {
        float s = 0.f;
        #pragma unroll
        for (int c = 0; c < DIMC; ++c) s += qt[c] * kb[c];
        qkb_s = s;
    }
    __syncthreads();

    const float* dp = dx + (size_t)(b * DIMC) * NTOK;
    float s = qkb_s;
    #pragma unroll
    for (int c = 0; c < DIMC; ++c) s += qk[c] * dp[c * NTOK + tid];
    s *= 0.125f;

    red[tid] = s;
    __syncthreads();
    for (int off = 512; off > 0; off >>= 1) {
        if (tid < off) red[tid] = fmaxf(red[tid], red[tid + off]);
        __syncthreads();
    }
    float m = red[0];
    __syncthreads();

    float e = __expf(s - m);
    sc[tid] = e;
    red[tid] = e;
    __syncthreads();
    for (int off = 512; off > 0; off >>= 1) {
        if (tid < off) red[tid] += red[tid + off];
        __syncthreads();
    }
    float Ssum = red[0];
    __syncthreads();

    const int c  = tid & 63, qq = tid >> 6;
    float part = 0.f;
    const float* dr = dp + c * NTOK + qq * 64;
    const float* sr = sc + qq * 64;
    #pragma unroll
    for (int n = 0; n < 64; ++n) part += sr[n] * dr[n];
    red[tid] = part;
    __syncthreads();
    if (tid < DIMC) {
        float u = 0.f;
        #pragma unroll
        for (int k = 0; k < 16; ++k) u += red[tid + k * 64];
        uN[tid] = u / Ssum;
    }
    __syncthreads();
    if (tid < DIMC) {
        float o = vb[tid];
        const float* vr = vw + tid * DIMC;
        #pragma unroll
        for (int cc = 0; cc < DIMC; ++cc) o += vr[cc] * uN[cc];
        osh[tid] = o;
    }
    __syncthreads();
    if (tid < DIMC) {
        float p = pb[tid];
        const float* pr = pw + tid * DIMC;
        #pragma unroll
        for (int cc = 0; cc < DIMC; ++cc) p += pr[cc] * osh[cc];
        psh[tid] = p;
    }
    __syncthreads();
    if (tid == 0) {
        float r = db[0];
        #pragma unroll
        for (int cc = 0; cc < DIMC; ++cc) r += psh[cc] * dw[cc];
        outv[bt] = r;
    }
}

// --- chunked sum of I2^dist per (b,c) --- [round 6 verbatim]
__global__ __launch_bounds__(256) void wb_reduce_kernel(const float* __restrict__ I2,
                                                        const float* __restrict__ attno,
                                                        float* __restrict__ part)
{
    __shared__ float red[256];
    const int bc = blockIdx.y;                 // b*3 + c
    const int b  = bc / 3;
    float d = attno[b * 10 + 9];
    d = fmaxf(d, 0.f) + 1.0f;
    constexpr int CHUNK = HW / WBCH;           // 8192 px
    const float4* base = (const float4*)(I2 + (size_t)bc * HW + blockIdx.x * CHUNK);
    float l = 0.f;
    #pragma unroll
    for (int i = threadIdx.x, it = 0; it < CHUNK / 4 / 256; ++it, i += 256) {
        float4 v = base[i];
        l += __expf(d * __logf(v.x)) + __expf(d * __logf(v.y))
           + __expf(d * __logf(v.z)) + __expf(d * __logf(v.w));
    }
    red[threadIdx.x] = l;
    __syncthreads();
    for (int off = 128; off > 0; off >>= 1) {
        if (threadIdx.x < off) red[threadIdx.x] += red[threadIdx.x + off];
        __syncthreads();
    }
    if (threadIdx.x == 0) part[bc * WBCH + blockIdx.x] = red[0];
}

// --- per-batch white-balance scale avg/ch from partials (trivial) ---
__global__ void wb_finalize_kernel(const float* __restrict__ part,
                                   const float* __restrict__ attno,
                                   float* __restrict__ wbsc)
{
    int b = threadIdx.x;
    if (b >= BB) return;
    float d = attno[b * 10 + 9];
    d = fmaxf(d, 0.f) + 1.0f;
    float inv = 1.0f / d;
    float s[3];
    #pragma unroll
    for (int c = 0; c < 3; ++c) {
        float t0 = 0.f;
        const float* pp = part + (b * 3 + c) * WBCH;
        #pragma unroll
        for (int k = 0; k < WBCH; ++k) t0 += pp[k];
        s[c] = t0;
    }
    float avg = powf((s[0] + s[1] + s[2]) / (3.0f * (float)HW), inv);
    #pragma unroll
    for (int c = 0; c < 3; ++c)
        wbsc[b * 4 + c] = avg / powf(s[c] / (float)HW, inv);
}

// --- fused WB + CCM + NILUT: layers 2-4 on MFMA f16 --- [round 5 form, passed]
__global__ void __launch_bounds__(256) final_kernel(
    float* __restrict__ io,
    const float* __restrict__ wbsc, const float* __restrict__ attno,
    const float* __restrict__ w0, const float* __restrict__ b0,
    const float* __restrict__ w1, const float* __restrict__ b1,
    const float* __restrict__ w2, const float* __restrict__ b2,
    const float* __restrict__ w3, const float* __restrict__ b3,
    const float* __restrict__ w4, const float* __restrict__ b4)
{
    constexpr int ROW = 72;                       // f16 per px row (144 B)
    __shared__ __align__(16) _Float16 LDS[4][64 * ROW];   // 36864 B
    const int tid  = threadIdx.x;
    const int wv   = tid >> 6;
    const int lane = tid & 63;
    const int nn   = lane & 15;
    const int quad = lane >> 4;
    _Float16* Wl = LDS[wv];

    const int b   = blockIdx.x >> 10;             // 1024 blocks per image
    const int pix = (blockIdx.x * 256 + tid) & (HW - 1);
    float* base = io + b * 3 * HW + pix;

    const float s0 = wbsc[b * 4 + 0], s1 = wbsc[b * 4 + 1], s2 = wbsc[b * 4 + 2];
    float v0 = base[0] * s0;
    float v1 = base[HW] * s1;
    float v2 = base[2 * HW] * s2;
    const float* o2p = attno + b * 10;            // block-uniform -> scalar
    float I4[3];
    #pragma unroll
    for (int d = 0; d < 3; ++d) {
        float m0 = 0.1f * o2p[d * 3]     + (d == 0 ? 1.f : 0.f);
        float m1 = 0.1f * o2p[d * 3 + 1] + (d == 1 ? 1.f : 0.f);
        float m2 = 0.1f * o2p[d * 3 + 2] + (d == 2 ? 1.f : 0.f);
        I4[d] = fminf(fmaxf(m0 * v0 + m1 * v1 + m2 * v2, 1e-5f), 1.0f);
    }

    #pragma unroll
    for (int j = 0; j < 32; j += 2) {
        float a0 = b0[j]   + w0[j*3]     * I4[0] + w0[j*3+1]     * I4[1] + w0[j*3+2]     * I4[2];
        float a1 = b0[j+1] + w0[(j+1)*3] * I4[0] + w0[(j+1)*3+1] * I4[1] + w0[(j+1)*3+2] * I4[2];
        f16x2 p;
        p[0] = (_Float16)fmaxf(a0, 0.f);
        p[1] = (_Float16)fmaxf(a1, 0.f);
        *(f16x2*)&Wl[lane * ROW + j] = p;
    }

    f16x8 wf[3][2];
    float bv[3][2];
    const float* wls[3] = { w1, w2, w3 };
    const float* bls[3] = { b1, b2, b3 };
    #pragma unroll
    for (int L = 0; L < 3; ++L) {
        #pragma unroll
        for (int h = 0; h < 2; ++h) {
            const float* wr = wls[L] + (16 * h + nn) * 32 + quad * 8;
            #pragma unroll
            for (int i = 0; i < 8; ++i) wf[L][h][i] = (_Float16)wr[i];
            bv[L][h] = bls[L][16 * h + nn];
        }
    }
    __syncthreads();

    #pragma unroll
    for (int L = 0; L < 3; ++L) {
        f16x8 af[4];
        #pragma unroll
        for (int t = 0; t < 4; ++t)
            af[t] = *(const f16x8*)&Wl[(16 * t + nn) * ROW + quad * 8];
        __syncthreads();
        #pragma unroll
        for (int t = 0; t < 4; ++t) {
            #pragma unroll
            for (int h = 0; h < 2; ++h) {
                f32x4 c;
                c[0] = c[1] = c[2] = c[3] = bv[L][h];
                f32x4 d = __builtin_amdgcn_mfma_f32_16x16x32_f16(af[t], wf[L][h], c, 0, 0, 0);
                #pragma unroll
                for (int r = 0; r < 4; ++r)
                    Wl[(16 * t + quad * 4 + r) * ROW + 16 * h + nn] = (_Float16)tanh_fast(d[r]);
            }
        }
        __syncthreads();
    }

    float h4[32];
    #pragma unroll
    for (int g = 0; g < 4; ++g) {
        f16x8 rv = *(const f16x8*)&Wl[lane * ROW + g * 8];
        #pragma unroll
        for (int i = 0; i < 8; ++i) h4[g * 8 + i] = (float)rv[i];
    }
    #pragma unroll
    for (int d = 0; d < 3; ++d) {
        float a = b4[d];
        const float* wr = w4 + d * 32;            // uniform -> s_load
        #pragma unroll
        for (int k = 0; k < 32; ++k) a += h4[k] * wr[k];
        a += I4[d];
        base[d * HW] = fminf(fmaxf(a, 0.f), 1.0f);
    }
}

extern "C" void kernel_launch(void* const* d_in, const int* in_sizes, int n_in,
                              void* d_out, int out_size, void* d_ws, size_t ws_size,
                              hipStream_t stream)
{
    const float* I1      = (const float*)d_in[0];
    const float* kp_q    = (const float*)d_in[1];
    const float* kp_c1w  = (const float*)d_in[2];  const float* kp_c1b = (const float*)d_in[3];
    const float* kp_c2w  = (const float*)d_in[4];  const float* kp_c2b = (const float*)d_in[5];
    const float* kp_c3w  = (const float*)d_in[6];  const float* kp_c3b = (const float*)d_in[7];
    const float* kp_c4w  = (const float*)d_in[8];  const float* kp_c4b = (const float*)d_in[9];
    const float* kp_kw   = (const float*)d_in[10]; const float* kp_vw  = (const float*)d_in[11];
    const float* kp_pw   = (const float*)d_in[12]; const float* kp_dw  = (const float*)d_in[13];
    const float* kp_kb   = (const float*)d_in[14]; const float* kp_vb  = (const float*)d_in[15];
    const float* kp_pb   = (const float*)d_in[16]; const float* kp_db  = (const float*)d_in[17];
    const float* mp_q    = (const float*)d_in[18];
    const float* mp_c1w  = (const float*)d_in[19]; const float* mp_c1b = (const float*)d_in[20];
    const float* mp_c2w  = (const float*)d_in[21]; const float* mp_c2b = (const float*)d_in[22];
    const float* mp_c3w  = (const float*)d_in[23]; const float* mp_c3b = (const float*)d_in[24];
    const float* mp_c4w  = (const float*)d_in[25]; const float* mp_c4b = (const float*)d_in[26];
    const float* mp_kw   = (const float*)d_in[27]; const float* mp_vw  = (const float*)d_in[28];
    const float* mp_pw   = (const float*)d_in[29]; const float* mp_dw  = (const float*)d_in[30];
    const float* mp_kb   = (const float*)d_in[31]; const float* mp_vb  = (const float*)d_in[32];
    const float* mp_pb   = (const float*)d_in[33]; const float* mp_db  = (const float*)d_in[34];
    const float* gainb   = (const float*)d_in[35];
    const float* lw0 = (const float*)d_in[36]; const float* lb0 = (const float*)d_in[37];
    const float* lw1 = (const float*)d_in[38]; const float* lb1 = (const float*)d_in[39];
    const float* lw2 = (const float*)d_in[40]; const float* lb2 = (const float*)d_in[41];
    const float* lw3 = (const float*)d_in[42]; const float* lb3 = (const float*)d_in[43];
    const float* lw4 = (const float*)d_in[44]; const float* lb4 = (const float*)d_in[45];

    float* ws    = (float*)d_ws;
    float* ds1   = ws;                          // 8*8*256*256   = 4194304
    float* ds2   = ds1 + 8 * 8 * 256 * 256;     // 8*16*128*128  = 2097152
    float* ds3   = ds2 + 8 * 16 * 128 * 128;    // 8*32*64*64    = 1048576
    float* ds4   = ds3 + 8 * 32 * 64 * 64;      // 8*64*32*32    = 524288
    float* attno = ds4 + 8 * 64 * 32 * 32;      // 128 (kp: b*4+t / mp: b*10+t)
    float* part  = attno + 128;                 // 24 * WBCH
    float* wbsc  = part + 24 * WBCH;            // 32
    float* I2    = (float*)d_out;               // I2 lives in d_out

    // --- Kernel_Predictor --- [round 6 configs]
    conv_s2<3, 512, 8, true ><<<dim3(256, 1, BB), 256, 0, stream>>>(I1,  kp_c1w, kp_c1b, ds1);
    conv_s2<8, 256, 8, true ><<<dim3(64,  2, BB), 256, 0, stream>>>(ds1, kp_c2w, kp_c2b, ds2);
    conv_s2<16, 128, 4, true><<<dim3(16,  8, BB), 256, 0, stream>>>(ds2, kp_c3w, kp_c3b, ds3);
    conv_s2<32, 64, 4, false><<<dim3(4,  16, BB), 256, 0, stream>>>(ds3, kp_c4w, kp_c4b, ds4);
    attn_kernel<<<BB * 4, 1024, 0, stream>>>(ds4, kp_q, kp_kw, kp_kb, kp_vw, kp_vb,
                                             kp_pw, kp_pb, kp_dw, kp_db, attno, 4);

    // --- denoise fused with conv1_mp: writes I2 (d_out) + ds1 ---
    denoise_conv1_kernel<<<dim3(256, 1, BB), 256, 0, stream>>>(I1, attno, gainb,
                                                               mp_c1w, mp_c1b, I2, ds1);

    // --- rest of Matrix_Predictor ---
    conv_s2<8, 256, 8, true ><<<dim3(64,  2, BB), 256, 0, stream>>>(ds1, mp_c2w, mp_c2b, ds2);
    conv_s2<16, 128, 4, true><<<dim3(16,  8, BB), 256, 0, stream>>>(ds2, mp_c3w, mp_c3b, ds3);
    conv_s2<32, 64, 4, false><<<dim3(4,  16, BB), 256, 0, stream>>>(ds3, mp_c4w, mp_c4b, ds4);
    attn_kernel<<<BB * 10, 1024, 0, stream>>>(ds4, mp_q, mp_kw, mp_kb, mp_vw, mp_vb,
                                              mp_pw, mp_pb, mp_dw, mp_db, attno, 10);

    // --- shades-of-gray reduction ---
    wb_reduce_kernel<<<dim3(WBCH, 24), 256, 0, stream>>>(I2, attno, part);
    wb_finalize_kernel<<<1, 64, 0, stream>>>(part, attno, wbsc);

    // --- fused WB + CCM + NILUT (in-place on d_out) ---
    final_kernel<<<BB * HW / 256, 256, 0, stream>>>(I2, wbsc, attno,
        lw0, lb0, lw1, lb1, lw2, lb2, lw3, lb3, lw4, lb4);
}